// Round 2
// baseline (792.030 us; speedup 1.0000x reference)
//
#include <hip/hip_runtime.h>
#include <hip/hip_bf16.h>
#include <math.h>

#define BB 4
#define LF 257      // NTOK+1
#define MR 1028     // BB*LF
#define DMODEL 384
#define DIN 768
#define NST 16
#define DTR 24
#define XDB 56      // DTR + 2*N
#define POSROW 128
#define CL 16       // scan chunk length
#define NC 17       // ceil(LF/CL)
#define NKC 8       // xp_k split-K chunks

typedef __attribute__((ext_vector_type(8))) short short8;
typedef __attribute__((ext_vector_type(4))) float f32x4;

__device__ __forceinline__ float siluf(float v) { return v / (1.f + __expf(-v)); }
__device__ __forceinline__ float softplusf(float v) {
    return (v > 20.f) ? v : log1pf(__expf(v));
}
__device__ __forceinline__ short f2bf(float f) {
    unsigned u = __builtin_bit_cast(unsigned, f);
    unsigned r = (u + 0x7FFFu + ((u >> 16) & 1u)) >> 16;
    return (short)r;
}

// ---------------------------------------------------------------------------
// bf16-MFMA GEMM core over K range [kb,ke): C[m,n] (+)= sum A[m,k]*W[n,k].
// 64x64 tile, 4 waves (2x2), each wave 2x2 mfma_f32_16x16x32_bf16.
// AMODE: 1 patch gather, 2 flip-add, 3 LN fused — stats computed IN-BLOCK
//        from the residual rows (L2-warm re-read; no stats buffer/coupling).
// SMODE: 0 plain(+bias), 3 patchify store (bias+pos, cls gap), 4 atomicAdd
// ---------------------------------------------------------------------------
template<int AMODE, int SMODE>
__device__ __forceinline__ void mgemm_core(
    const float* __restrict__ A, int lda,
    const float* __restrict__ W,
    const float* __restrict__ bias,
    float* __restrict__ Cout, int M, int N, int K, int kb, int ke,
    int bm, int bn,
    const float* __restrict__ gA, const float* __restrict__ A2,
    const float* __restrict__ pos,
    short* __restrict__ Ab, short* __restrict__ Wb)
{
    const int tid = threadIdx.x;
    const int m_s = tid >> 2;
    const int q_s = tid & 3;
    const int lane = tid & 63;
    const int wv = tid >> 6;
    const int wm = (wv >> 1) * 32, wn = (wv & 1) * 32;
    const int qq = lane >> 4, lr = lane & 15;

    f32x4 acc[2][2];
    #pragma unroll
    for (int i = 0; i < 2; ++i)
        #pragma unroll
        for (int j = 0; j < 2; ++j)
            acc[i][j] = f32x4{0.f, 0.f, 0.f, 0.f};

    // AMODE 3: per-row LN stats computed here, from the rows this block
    // re-reads during staging anyway (L2-warm). 4 threads share a row.
    float2 stf = make_float2(0.f, 0.f);
    if (AMODE == 3) {
        int m = bm + m_s;
        float s = 0.f, q = 0.f;
        if (m < M) {
            const float* row = &A[(size_t)m * lda];
            for (int k = q_s * 8; k < K; k += 32) {
                float4 v0 = *(const float4*)&row[k];
                float4 v1 = *(const float4*)&row[k + 4];
                s += v0.x + v0.y + v0.z + v0.w + v1.x + v1.y + v1.z + v1.w;
                q += v0.x * v0.x + v0.y * v0.y + v0.z * v0.z + v0.w * v0.w
                   + v1.x * v1.x + v1.y * v1.y + v1.z * v1.z + v1.w * v1.w;
            }
        }
        s += __shfl_xor(s, 1); s += __shfl_xor(s, 2);
        q += __shfl_xor(q, 1); q += __shfl_xor(q, 2);
        float mean = s * (1.f / 384.f);
        float var = q * (1.f / 384.f) - mean * mean;
        stf = make_float2(mean, rsqrtf(var + 1e-5f));
    }

    float4 pa[2], pw[2];
    const float4 z4 = make_float4(0.f, 0.f, 0.f, 0.f);

    auto loadA = [&](int k0) {
        int k = k0 + q_s * 8;
        int m = bm + m_s;
        if (AMODE == 1) {
            int b = m >> 8, t = m & 255;
            int gh = t >> 3, gw = t & 7;
            int p1 = k >> 4, p2 = k & 15;
            const float* src = &gA[(size_t)b * 65536 + gh * 2048 + p1 * 128 + gw * 16 + p2];
            pa[0] = *(const float4*)src;
            pa[1] = *(const float4*)(src + 4);
        } else if (AMODE == 2) {  // flip-add
            if (m < M && k < K) {
                int b = m / LF, l = m - b * LF;
                const float* s1 = &A[(size_t)m * lda + k];
                const float* s2 = &A2[(size_t)(b * LF + (LF - 1 - l)) * lda + k];
                float4 x0 = *(const float4*)s1, x1 = *(const float4*)(s1 + 4);
                float4 y0 = *(const float4*)s2, y1 = *(const float4*)(s2 + 4);
                pa[0] = make_float4(x0.x + y0.x, x0.y + y0.y, x0.z + y0.z, x0.w + y0.w);
                pa[1] = make_float4(x1.x + y1.x, x1.y + y1.y, x1.z + y1.z, x1.w + y1.w);
            } else { pa[0] = z4; pa[1] = z4; }
        } else {  // AMODE 3: LayerNorm fused during staging
            if (m < M && k < K) {
                float4 r0 = *(const float4*)&A[(size_t)m * lda + k];
                float4 r1 = *(const float4*)&A[(size_t)m * lda + k + 4];
                float4 w0 = *(const float4*)&A2[k],  w1 = *(const float4*)&A2[k + 4];
                float4 b0 = *(const float4*)&pos[k], b1 = *(const float4*)&pos[k + 4];
                pa[0] = make_float4((r0.x - stf.x) * stf.y * w0.x + b0.x,
                                    (r0.y - stf.x) * stf.y * w0.y + b0.y,
                                    (r0.z - stf.x) * stf.y * w0.z + b0.z,
                                    (r0.w - stf.x) * stf.y * w0.w + b0.w);
                pa[1] = make_float4((r1.x - stf.x) * stf.y * w1.x + b1.x,
                                    (r1.y - stf.x) * stf.y * w1.y + b1.y,
                                    (r1.z - stf.x) * stf.y * w1.z + b1.z,
                                    (r1.w - stf.x) * stf.y * w1.w + b1.w);
            } else { pa[0] = z4; pa[1] = z4; }
        }
    };
    auto loadW = [&](int k0) {
        int k = k0 + q_s * 8;
        int n = bn + m_s;
        if (n < N && k < K) {
            pw[0] = *(const float4*)&W[(size_t)n * K + k];
            pw[1] = *(const float4*)&W[(size_t)n * K + k + 4];
        } else { pw[0] = z4; pw[1] = z4; }
    };
    auto cvt8 = [&](float4 a, float4 b) -> short8 {
        short8 r;
        r[0] = f2bf(a.x); r[1] = f2bf(a.y); r[2] = f2bf(a.z); r[3] = f2bf(a.w);
        r[4] = f2bf(b.x); r[5] = f2bf(b.y); r[6] = f2bf(b.z); r[7] = f2bf(b.w);
        return r;
    };

    loadA(kb);
    loadW(kb);

    int s = 0;
    for (int k0 = kb; k0 < ke; k0 += 32, ++s) {
        const int buf = (s & 1) * 2048;
        *(short8*)&Ab[buf + (q_s * 64 + m_s) * 8] = cvt8(pa[0], pa[1]);
        *(short8*)&Wb[buf + (q_s * 64 + m_s) * 8] = cvt8(pw[0], pw[1]);
        __syncthreads();
        if (k0 + 32 < ke) { loadA(k0 + 32); loadW(k0 + 32); }
        short8 af0 = *(const short8*)&Ab[buf + (qq * 64 + wm + lr) * 8];
        short8 af1 = *(const short8*)&Ab[buf + (qq * 64 + wm + 16 + lr) * 8];
        short8 wf0 = *(const short8*)&Wb[buf + (qq * 64 + wn + lr) * 8];
        short8 wf1 = *(const short8*)&Wb[buf + (qq * 64 + wn + 16 + lr) * 8];
        acc[0][0] = __builtin_amdgcn_mfma_f32_16x16x32_bf16(af0, wf0, acc[0][0], 0, 0, 0);
        acc[0][1] = __builtin_amdgcn_mfma_f32_16x16x32_bf16(af0, wf1, acc[0][1], 0, 0, 0);
        acc[1][0] = __builtin_amdgcn_mfma_f32_16x16x32_bf16(af1, wf0, acc[1][0], 0, 0, 0);
        acc[1][1] = __builtin_amdgcn_mfma_f32_16x16x32_bf16(af1, wf1, acc[1][1], 0, 0, 0);
    }

    #pragma unroll
    for (int mi = 0; mi < 2; ++mi) {
        #pragma unroll
        for (int ni = 0; ni < 2; ++ni) {
            int col = bn + wn + ni * 16 + lr;
            if (col >= N) continue;
            #pragma unroll
            for (int r = 0; r < 4; ++r) {
                int row = bm + wm + mi * 16 + qq * 4 + r;
                if (row >= M) continue;
                float v = acc[mi][ni][r];
                if (SMODE == 0) {
                    if (bias) v += bias[col];
                    Cout[(size_t)row * N + col] = v;
                } else if (SMODE == 3) {
                    int b = row >> 8, t = row & 255;
                    int l = (t < POSROW) ? t : t + 1;
                    v += bias[col] + pos[(size_t)l * DMODEL + col];
                    Cout[(size_t)(b * LF + l) * DMODEL + col] = v;
                } else {  // SMODE 4
                    atomicAdd(&Cout[(size_t)row * N + col], v);
                }
            }
        }
    }
}

template<int AMODE, int SMODE>
__global__ __launch_bounds__(256) void mgemm_k(
    const float* __restrict__ A, int lda,
    const float* __restrict__ W, const float* __restrict__ bias,
    float* __restrict__ Cout, int M, int N, int K, int KS,
    const float* __restrict__ gA, const float* __restrict__ A2,
    const float* __restrict__ pos)
{
    __shared__ __align__(16) short Ab[2 * 2048];
    __shared__ __align__(16) short Wb[2 * 2048];
    // XCD-aware bijective swizzle: hw round-robins blocks over 8 XCDs;
    // remap so each XCD gets a CONTIGUOUS logical chunk (shared W panel -> L2)
    int nwg = gridDim.x * gridDim.y;
    int lin = blockIdx.x + blockIdx.y * gridDim.x;
    if ((nwg & 7) == 0) {
        int ch = nwg >> 3;
        lin = (lin & 7) * ch + (lin >> 3);
    }
    int bx = lin % gridDim.x;
    int by = lin / gridDim.x;
    int ntile = by / KS, ks = by % KS;
    int chunk = K / KS;
    mgemm_core<AMODE, SMODE>(A, lda, W, bias, Cout, M, N, K,
                             ks * chunk, ks * chunk + chunk, bx * 64, ntile * 64,
                             gA, A2, pos, Ab, Wb);
}

// ---------------------------------------------------------------------------
// Fused conv(K=4)+SiLU -> xproj MFMA. grid (17 m-tiles, NKC k-chunks, 2 br).
// Writes xc side-product and NON-ATOMIC split-K partials to plane kc of
// xdb_part[NKC][MR][XDB] (summed in the scan kernels; no memset needed).
// ---------------------------------------------------------------------------
__global__ __launch_bounds__(256) void xp_k(
    const float* __restrict__ xz,
    const float* __restrict__ cwf, const float* __restrict__ cbf,
    const float* __restrict__ cwb, const float* __restrict__ cbb,
    const float* __restrict__ Wf, const float* __restrict__ Wb,
    float* __restrict__ xcf, float* __restrict__ xcb,
    float* __restrict__ xdbf, float* __restrict__ xdbb)
{
    __shared__ __align__(16) short Ash[2 * 2048];
    __shared__ __align__(16) short Wsh[2 * 2048];
    const int br = blockIdx.z;
    const int kcid = blockIdx.y;
    const float* cw = br ? cwb : cwf;
    const float* cbv = br ? cbb : cbf;
    const float* W  = br ? Wb  : Wf;
    float* xco      = br ? xcb : xcf;
    float* xdo      = br ? xdbb : xdbf;

    const int tid = threadIdx.x;
    const int m_s = tid >> 2, q_s = tid & 3;
    const int bm = blockIdx.x * 64;
    const int kb = kcid * 96;
    const int lane = tid & 63, wv = tid >> 6;
    const int wm = (wv >> 1) * 32, wn = (wv & 1) * 32;
    const int qq = lane >> 4, lr = lane & 15;
    const int m = bm + m_s;
    const bool mok = (m < MR);
    int b = 0, l = 0;
    if (mok) { b = m / LF; l = m - b * LF; }

    f32x4 acc[2][2];
    #pragma unroll
    for (int i = 0; i < 2; ++i)
        #pragma unroll
        for (int j = 0; j < 2; ++j)
            acc[i][j] = f32x4{0.f, 0.f, 0.f, 0.f};

    float a8[8];
    float4 pw0, pw1;
    const float4 z4 = make_float4(0.f, 0.f, 0.f, 0.f);

    auto loadA = [&](int k0) {
        int d0 = k0 + q_s * 8;
        if (mok) {
            float4 c0 = *(const float4*)&cbv[d0];
            float4 c1 = *(const float4*)&cbv[d0 + 4];
            a8[0] = c0.x; a8[1] = c0.y; a8[2] = c0.z; a8[3] = c0.w;
            a8[4] = c1.x; a8[5] = c1.y; a8[6] = c1.z; a8[7] = c1.w;
            float wreg[8][4];
            #pragma unroll
            for (int j = 0; j < 8; ++j)
                *(float4*)wreg[j] = *(const float4*)&cw[(d0 + j) * 4];
            #pragma unroll
            for (int kk = 0; kk < 4; ++kk) {
                int li = l - 3 + kk;
                if (li >= 0) {
                    int srow = br ? (b * LF + (LF - 1 - li)) : (b * LF + li);
                    const float* xp = &xz[(size_t)srow * 2 * DIN + d0];
                    float4 x0 = *(const float4*)xp, x1 = *(const float4*)(xp + 4);
                    a8[0] += x0.x * wreg[0][kk]; a8[1] += x0.y * wreg[1][kk];
                    a8[2] += x0.z * wreg[2][kk]; a8[3] += x0.w * wreg[3][kk];
                    a8[4] += x1.x * wreg[4][kk]; a8[5] += x1.y * wreg[5][kk];
                    a8[6] += x1.z * wreg[6][kk]; a8[7] += x1.w * wreg[7][kk];
                }
            }
            #pragma unroll
            for (int j = 0; j < 8; ++j) a8[j] = siluf(a8[j]);
        } else {
            #pragma unroll
            for (int j = 0; j < 8; ++j) a8[j] = 0.f;
        }
    };
    auto loadW = [&](int k0) {
        int k = k0 + q_s * 8;
        if (m_s < XDB) {
            pw0 = *(const float4*)&W[(size_t)m_s * DIN + k];
            pw1 = *(const float4*)&W[(size_t)m_s * DIN + k + 4];
        } else { pw0 = z4; pw1 = z4; }
    };
    auto cvt8f = [&]() -> short8 {
        short8 r;
        #pragma unroll
        for (int j = 0; j < 8; ++j) r[j] = f2bf(a8[j]);
        return r;
    };
    auto cvt8w = [&]() -> short8 {
        short8 r;
        r[0] = f2bf(pw0.x); r[1] = f2bf(pw0.y); r[2] = f2bf(pw0.z); r[3] = f2bf(pw0.w);
        r[4] = f2bf(pw1.x); r[5] = f2bf(pw1.y); r[6] = f2bf(pw1.z); r[7] = f2bf(pw1.w);
        return r;
    };

    loadA(kb);
    loadW(kb);

    #pragma unroll
    for (int s = 0; s < 3; ++s) {
        const int k0 = kb + s * 32;
        const int buf = (s & 1) * 2048;
        *(short8*)&Ash[buf + (q_s * 64 + m_s) * 8] = cvt8f();
        *(short8*)&Wsh[buf + (q_s * 64 + m_s) * 8] = cvt8w();
        if (mok) {  // side-product: materialize xc for the scan kernels
            int d0 = k0 + q_s * 8;
            *(float4*)&xco[(size_t)m * DIN + d0] =
                make_float4(a8[0], a8[1], a8[2], a8[3]);
            *(float4*)&xco[(size_t)m * DIN + d0 + 4] =
                make_float4(a8[4], a8[5], a8[6], a8[7]);
        }
        __syncthreads();
        if (s + 1 < 3) { loadA(k0 + 32); loadW(k0 + 32); }
        short8 af0 = *(const short8*)&Ash[buf + (qq * 64 + wm + lr) * 8];
        short8 af1 = *(const short8*)&Ash[buf + (qq * 64 + wm + 16 + lr) * 8];
        short8 wf0 = *(const short8*)&Wsh[buf + (qq * 64 + wn + lr) * 8];
        short8 wf1 = *(const short8*)&Wsh[buf + (qq * 64 + wn + 16 + lr) * 8];
        acc[0][0] = __builtin_amdgcn_mfma_f32_16x16x32_bf16(af0, wf0, acc[0][0], 0, 0, 0);
        acc[0][1] = __builtin_amdgcn_mfma_f32_16x16x32_bf16(af0, wf1, acc[0][1], 0, 0, 0);
        acc[1][0] = __builtin_amdgcn_mfma_f32_16x16x32_bf16(af1, wf0, acc[1][0], 0, 0, 0);
        acc[1][1] = __builtin_amdgcn_mfma_f32_16x16x32_bf16(af1, wf1, acc[1][1], 0, 0, 0);
        if (s + 1 < 3) __syncthreads();
    }

    #pragma unroll
    for (int mi = 0; mi < 2; ++mi) {
        #pragma unroll
        for (int ni = 0; ni < 2; ++ni) {
            int col = wn + ni * 16 + lr;
            if (col >= XDB) continue;
            #pragma unroll
            for (int r = 0; r < 4; ++r) {
                int row = bm + wm + mi * 16 + qq * 4 + r;
                if (row >= MR) continue;
                xdo[((size_t)kcid * MR + row) * XDB + col] = acc[mi][ni][r];
            }
        }
    }
}

// cls row: residual[b, 128, :] = cls + pos[128]
__global__ void cls_k(const float* __restrict__ cls, const float* __restrict__ pos,
                      float* __restrict__ residual) {
    int b = blockIdx.x, t = threadIdx.x;
    residual[(size_t)(b * LF + POSROW) * DMODEL + t] =
        cls[t] + pos[(size_t)POSROW * DMODEL + t];
}

// ---------------------------------------------------------------------------
// Chunked associative scan with FUSED dt-projection+softplus.
// xdb arrives as NKC non-atomic split-K planes; summed during LDS staging.
// ---------------------------------------------------------------------------
__global__ __launch_bounds__(256) void scanA_k(
    const float* __restrict__ xcf, const float* __restrict__ xcb,
    const float* __restrict__ xdbf, const float* __restrict__ xdbb,
    const float* __restrict__ alf, const float* __restrict__ alb,
    const float* __restrict__ dwf, const float* __restrict__ dbf,
    const float* __restrict__ dwb, const float* __restrict__ dbb,
    float* __restrict__ hpart, float* __restrict__ sumd) {
    const int t = threadIdx.x;
    const int y = blockIdx.y;            // b*2+br
    const int b = y >> 1, br = y & 1;
    const int c = blockIdx.z;
    const int d = blockIdx.x * 256 + t;
    const float* xc  = br ? xcb  : xcf;
    const float* xdb = br ? xdbb : xdbf;
    const float* Al  = br ? alb  : alf;
    const float* dw  = br ? dwb  : dwf;
    const float* dbi = br ? dbb  : dbf;

    float An[NST];
    #pragma unroll
    for (int n = 0; n < NST; ++n) An[n] = -__expf(Al[(size_t)d * NST + n]);
    float wdt[DTR];
    #pragma unroll
    for (int k = 0; k < DTR; k += 4)
        *(float4*)&wdt[k] = *(const float4*)&dw[(size_t)d * DTR + k];
    float dbv = dbi[d];

    const size_t PL = (size_t)MR * XDB;
    __shared__ float sXD[CL][DTR];
    __shared__ float sB[CL][NST];
    for (int idx = t; idx < CL * DTR; idx += 256) {
        int s0 = idx / DTR, j0 = idx - s0 * DTR;
        int l0 = c * CL + s0;
        float v = 0.f;
        if (l0 < LF) {
            size_t ba = (size_t)(b * LF + l0) * XDB + j0;
            #pragma unroll
            for (int kc = 0; kc < NKC; ++kc) v += xdb[kc * PL + ba];
        }
        sXD[s0][j0] = v;
    }
    {
        int s0 = t >> 4, j0 = t & 15;
        int l0 = c * CL + s0;
        float v = 0.f;
        if (l0 < LF) {
            size_t ba = (size_t)(b * LF + l0) * XDB + DTR + j0;
            #pragma unroll
            for (int kc = 0; kc < NKC; ++kc) v += xdb[kc * PL + ba];
        }
        sB[s0][j0] = v;
    }
    __syncthreads();

    float h[NST] = {};
    float sdt = 0.f;
    #pragma unroll
    for (int s = 0; s < CL; ++s) {
        int l = c * CL + s;
        if (l < LF) {
            int row = b * LF + l;
            float dtv = dbv;
            #pragma unroll
            for (int k = 0; k < DTR; ++k) dtv += sXD[s][k] * wdt[k];
            dtv = softplusf(dtv);
            float xcv = xc[(size_t)row * DIN + d];
            sdt += dtv;
            float dtx = dtv * xcv;
            #pragma unroll
            for (int n = 0; n < NST; ++n)
                h[n] = __expf(dtv * An[n]) * h[n] + dtx * sB[s][n];
        }
    }
    size_t base = (size_t)(c * 8 + y) * NST;
    #pragma unroll
    for (int n = 0; n < NST; ++n) hpart[(base + n) * DIN + d] = h[n];
    sumd[(size_t)(c * 8 + y) * DIN + d] = sdt;
}

__global__ __launch_bounds__(256) void scanC_k(
    const float* __restrict__ xcf, const float* __restrict__ xcb,
    const float* __restrict__ xdbf, const float* __restrict__ xdbb,
    const float* __restrict__ xz,
    const float* __restrict__ alf, const float* __restrict__ dpf,
    const float* __restrict__ alb, const float* __restrict__ dpb,
    const float* __restrict__ dwf, const float* __restrict__ dbf,
    const float* __restrict__ dwb, const float* __restrict__ dbb,
    const float* __restrict__ hpart, const float* __restrict__ sumd,
    float* __restrict__ yf, float* __restrict__ yb) {
    const int t = threadIdx.x;
    const int y = blockIdx.y;
    const int b = y >> 1, br = y & 1;
    const int c = blockIdx.z;
    const int d = blockIdx.x * 256 + t;
    const float* xc  = br ? xcb  : xcf;
    const float* xdb = br ? xdbb : xdbf;
    const float* Al  = br ? alb  : alf;
    const float* Dpp = br ? dpb  : dpf;
    const float* dw  = br ? dwb  : dwf;
    const float* dbi = br ? dbb  : dbf;
    float* yo        = br ? yb   : yf;

    float An[NST];
    #pragma unroll
    for (int n = 0; n < NST; ++n) An[n] = -__expf(Al[(size_t)d * NST + n]);
    float wdt[DTR];
    #pragma unroll
    for (int k = 0; k < DTR; k += 4)
        *(float4*)&wdt[k] = *(const float4*)&dw[(size_t)d * DTR + k];
    float dbv = dbi[d];
    float Dv = Dpp[d];

    const size_t PL = (size_t)MR * XDB;
    __shared__ float sXD[CL][DTR];
    __shared__ float sB[CL][NST];
    __shared__ float sC[CL][NST];
    for (int idx = t; idx < CL * DTR; idx += 256) {
        int s0 = idx / DTR, j0 = idx - s0 * DTR;
        int l0 = c * CL + s0;
        float v = 0.f;
        if (l0 < LF) {
            size_t ba = (size_t)(b * LF + l0) * XDB + j0;
            #pragma unroll
            for (int kc = 0; kc < NKC; ++kc) v += xdb[kc * PL + ba];
        }
        sXD[s0][j0] = v;
    }
    {
        int s0 = t >> 4, j0 = t & 15;
        int l0 = c * CL + s0;
        float vB = 0.f, vC = 0.f;
        if (l0 < LF) {
            size_t rb = (size_t)(b * LF + l0) * XDB + DTR;
            #pragma unroll
            for (int kc = 0; kc < NKC; ++kc) {
                vB += xdb[kc * PL + rb + j0];
                vC += xdb[kc * PL + rb + NST + j0];
            }
        }
        sB[s0][j0] = vB;
        sC[s0][j0] = vC;
    }
    __syncthreads();

    float h[NST] = {};
    for (int j = 0; j < c; ++j) {
        float sd = sumd[(size_t)(j * 8 + y) * DIN + d];
        size_t base = (size_t)(j * 8 + y) * NST;
        #pragma unroll
        for (int n = 0; n < NST; ++n)
            h[n] = __expf(An[n] * sd) * h[n] + hpart[(base + n) * DIN + d];
    }

    #pragma unroll
    for (int s = 0; s < CL; ++s) {
        int l = c * CL + s;
        if (l < LF) {
            int row = b * LF + l;
            float dtv = dbv;
            #pragma unroll
            for (int k = 0; k < DTR; ++k) dtv += sXD[s][k] * wdt[k];
            dtv = softplusf(dtv);
            float xcv = xc[(size_t)row * DIN + d];
            int zl = br ? (LF - 1 - l) : l;
            float zv = xz[(size_t)(b * LF + zl) * (2 * DIN) + DIN + d];
            float dtx = dtv * xcv;
            float acc = 0.f;
            #pragma unroll
            for (int n = 0; n < NST; ++n) {
                h[n] = __expf(dtv * An[n]) * h[n] + dtx * sB[s][n];
                acc += h[n] * sC[s][n];
            }
            yo[(size_t)row * DIN + d] = (acc + xcv * Dv) * siluf(zv);
        }
    }
}

// final LN(row POS) + command MLP + add -> f32 out
__global__ __launch_bounds__(384) void final_k(
    const float* __restrict__ residual,
    const float* __restrict__ lnw, const float* __restrict__ lnb,
    const float* __restrict__ sv, const float* __restrict__ act,
    const float* __restrict__ cw1, const float* __restrict__ cb1,
    const float* __restrict__ cw2, const float* __restrict__ cb2,
    float* __restrict__ out) {
    int b = blockIdx.x, t = threadIdx.x;
    const float* x = residual + (size_t)(b * LF + POSROW) * DMODEL;
    float v = x[t];
    float s = v, sq = v * v;
    #pragma unroll
    for (int o = 32; o > 0; o >>= 1) {
        s += __shfl_down(s, o);
        sq += __shfl_down(sq, o);
    }
    __shared__ float ls[6], lq[6], hid[DMODEL], cmdin[20];
    if ((t & 63) == 0) { ls[t >> 6] = s; lq[t >> 6] = sq; }
    if (t < 20) cmdin[t] = (t < 16) ? sv[b * 16 + t] : act[b * 4 + t - 16];
    __syncthreads();
    float S = 0.f, Q = 0.f;
    #pragma unroll
    for (int w = 0; w < 6; ++w) { S += ls[w]; Q += lq[w]; }
    float mean = S * (1.f / 384.f);
    float var = Q * (1.f / 384.f) - mean * mean;
    float rs = rsqrtf(var + 1e-5f);
    float vis = (v - mean) * rs * lnw[t] + lnb[t];
    float a1 = cb1[t];
    #pragma unroll
    for (int k = 0; k < 20; ++k) a1 += cmdin[k] * cw1[t * 20 + k];
    hid[t] = fmaxf(a1, 0.f);
    __syncthreads();
    float a2 = cb2[t];
    for (int k = 0; k < DMODEL; ++k) a2 += hid[k] * cw2[t * DMODEL + k];
    out[b * DMODEL + t] = vis + a2;
}

extern "C" void kernel_launch(void* const* d_in, const int* in_sizes, int n_in,
                              void* d_out, int out_size, void* d_ws, size_t ws_size,
                              hipStream_t stream) {
    const float* depth_seq = (const float*)d_in[0];
    const float* state_vec = (const float*)d_in[1];
    const float* action    = (const float*)d_in[2];
    const float* patch_w   = (const float*)d_in[3];
    const float* patch_b   = (const float*)d_in[4];
    const float* cls_token = (const float*)d_in[5];
    const float* pos_embed = (const float*)d_in[6];
    const float* ln_w      = (const float*)d_in[7];
    const float* ln_b      = (const float*)d_in[8];
    const float* in_proj_w = (const float*)d_in[9];
    const float* conv_w    = (const float*)d_in[10];
    const float* conv_b    = (const float*)d_in[11];
    const float* conv_wb   = (const float*)d_in[12];
    const float* conv_bb   = (const float*)d_in[13];
    const float* xproj_w   = (const float*)d_in[14];
    const float* xproj_wb  = (const float*)d_in[15];
    const float* dtproj_w  = (const float*)d_in[16];
    const float* dtproj_b  = (const float*)d_in[17];
    const float* dtproj_wb = (const float*)d_in[18];
    const float* dtproj_bb = (const float*)d_in[19];
    const float* A_log     = (const float*)d_in[20];
    const float* A_logb    = (const float*)d_in[21];
    const float* Dp        = (const float*)d_in[22];
    const float* Dpb       = (const float*)d_in[23];
    const float* out_w     = (const float*)d_in[24];
    const float* lnf_w     = (const float*)d_in[25];
    const float* lnf_b     = (const float*)d_in[26];
    const float* cw1       = (const float*)d_in[27];
    const float* cb1       = (const float*)d_in[28];
    const float* cw2       = (const float*)d_in[29];
    const float* cb2       = (const float*)d_in[30];

    float* ws = (float*)d_ws;
    size_t o = 0;
    float* residual = ws + o; o += (size_t)MR * DMODEL;
    float* xz       = ws + o; o += (size_t)MR * 2 * DIN;
    float* xcf      = ws + o; o += (size_t)MR * DIN;
    float* xcb      = ws + o; o += (size_t)MR * DIN;
    float* xdbf     = ws + o; o += (size_t)NKC * MR * XDB;
    float* xdbb     = ws + o; o += (size_t)NKC * MR * XDB;
    float* yfb      = ws + o; o += (size_t)MR * DIN;
    float* ybb      = ws + o; o += (size_t)MR * DIN;
    float* hpart    = ws + o; o += (size_t)NC * 8 * NST * DIN;
    float* sumd     = ws + o; o += (size_t)NC * 8 * DIN;
    (void)ws_size; (void)in_sizes; (void)n_in; (void)out_size;

    // patchify -> residual (bias + pos, cls gap), MFMA
    mgemm_k<1, 3><<<dim3(16, 6), 256, 0, stream>>>(
        nullptr, 0, patch_w, patch_b, residual, 1024, DMODEL, 256, 1,
        depth_seq, nullptr, pos_embed);
    cls_k<<<BB, DMODEL, 0, stream>>>(cls_token, pos_embed, residual);

    for (int i = 0; i < 4; ++i) {
        // in_proj with LN fused (stats computed in-block): 1028x384 @ 384x1536^T
        mgemm_k<3, 0><<<dim3(17, 24), 256, 0, stream>>>(
            residual, DMODEL, in_proj_w + (size_t)i * 2 * DIN * DMODEL, nullptr,
            xz, MR, 2 * DIN, DMODEL, 1,
            nullptr, ln_w + (size_t)i * DMODEL, ln_b + (size_t)i * DMODEL);
        // fused conv+SiLU + xproj (writes xcf/xcb + split-K partial planes)
        xp_k<<<dim3(17, NKC, 2), 256, 0, stream>>>(
            xz, conv_w + (size_t)i * DIN * 4, conv_b + (size_t)i * DIN,
            conv_wb + (size_t)i * DIN * 4, conv_bb + (size_t)i * DIN,
            xproj_w + (size_t)i * XDB * DIN, xproj_wb + (size_t)i * XDB * DIN,
            xcf, xcb, xdbf, xdbb);
        // chunked scan with fused dt-projection
        scanA_k<<<dim3(3, 8, NC), 256, 0, stream>>>(
            xcf, xcb, xdbf, xdbb,
            A_log + (size_t)i * DIN * NST, A_logb + (size_t)i * DIN * NST,
            dtproj_w + (size_t)i * DIN * DTR, dtproj_b + (size_t)i * DIN,
            dtproj_wb + (size_t)i * DIN * DTR, dtproj_bb + (size_t)i * DIN,
            hpart, sumd);
        scanC_k<<<dim3(3, 8, NC), 256, 0, stream>>>(
            xcf, xcb, xdbf, xdbb, xz,
            A_log + (size_t)i * DIN * NST, Dp + (size_t)i * DIN,
            A_logb + (size_t)i * DIN * NST, Dpb + (size_t)i * DIN,
            dtproj_w + (size_t)i * DIN * DTR, dtproj_b + (size_t)i * DIN,
            dtproj_wb + (size_t)i * DIN * DTR, dtproj_bb + (size_t)i * DIN,
            hpart, sumd, yfb, ybb);
        // out_proj flip-add, split-K 4, atomicAdd accumulate into residual
        mgemm_k<2, 4><<<dim3(17, 6 * 4), 256, 0, stream>>>(
            yfb, DIN, out_w + (size_t)i * DMODEL * DIN, nullptr,
            residual, MR, DMODEL, DIN, 4, nullptr, ybb, nullptr);
    }

    final_k<<<BB, DMODEL, 0, stream>>>(
        residual, lnf_w, lnf_b, state_vec, action, cw1, cb1, cw2, cb2,
        (float*)d_out);
}

// Round 4
// 677.010 us; speedup vs baseline: 1.1699x; 1.1699x over previous
//
#include <hip/hip_runtime.h>
#include <hip/hip_bf16.h>
#include <math.h>

#define BB 4
#define LF 257      // NTOK+1
#define MR 1028     // BB*LF
#define DMODEL 384
#define DIN 768
#define NST 16
#define DTR 24
#define XDB 56      // DTR + 2*N
#define POSROW 128
#define CL 16       // scan chunk length
#define NC 17       // ceil(LF/CL)
#define NKC 8       // xp_k split-K chunks

typedef __attribute__((ext_vector_type(8))) short short8;
typedef __attribute__((ext_vector_type(4))) float f32x4;

__device__ __forceinline__ float siluf(float v) { return v / (1.f + __expf(-v)); }
__device__ __forceinline__ float softplusf(float v) {
    return (v > 20.f) ? v : log1pf(__expf(v));
}
__device__ __forceinline__ short f2bf(float f) {
    unsigned u = __builtin_bit_cast(unsigned, f);
    unsigned r = (u + 0x7FFFu + ((u >> 16) & 1u)) >> 16;
    return (short)r;
}

// ---------------------------------------------------------------------------
// bf16-MFMA GEMM core over K range [kb,ke): C[m,n] (+)= sum A[m,k]*W[n,k].
// 64x64 tile, 4 waves (2x2), each wave 2x2 mfma_f32_16x16x32_bf16.
// AMODE: 1 patch gather, 2 flip-add, 3 LN fused — stats computed IN-BLOCK
//        from the residual rows (L2-warm re-read).
// SMODE: 0 plain(+bias), 3 patchify store (bias+pos, cls gap), 4 atomicAdd
// ---------------------------------------------------------------------------
template<int AMODE, int SMODE>
__device__ __forceinline__ void mgemm_core(
    const float* __restrict__ A, int lda,
    const float* __restrict__ W,
    const float* __restrict__ bias,
    float* __restrict__ Cout, int M, int N, int K, int kb, int ke,
    int bm, int bn,
    const float* __restrict__ gA, const float* __restrict__ A2,
    const float* __restrict__ pos,
    short* __restrict__ Ab, short* __restrict__ Wb)
{
    const int tid = threadIdx.x;
    const int m_s = tid >> 2;
    const int q_s = tid & 3;
    const int lane = tid & 63;
    const int wv = tid >> 6;
    const int wm = (wv >> 1) * 32, wn = (wv & 1) * 32;
    const int qq = lane >> 4, lr = lane & 15;

    f32x4 acc[2][2];
    #pragma unroll
    for (int i = 0; i < 2; ++i)
        #pragma unroll
        for (int j = 0; j < 2; ++j)
            acc[i][j] = f32x4{0.f, 0.f, 0.f, 0.f};

    // AMODE 3: per-row LN stats computed in-block (rows are L2-warm)
    float2 stf = make_float2(0.f, 0.f);
    if (AMODE == 3) {
        int m = bm + m_s;
        float s = 0.f, q = 0.f;
        if (m < M) {
            const float* row = &A[(size_t)m * lda];
            for (int k = q_s * 8; k < K; k += 32) {
                float4 v0 = *(const float4*)&row[k];
                float4 v1 = *(const float4*)&row[k + 4];
                s += v0.x + v0.y + v0.z + v0.w + v1.x + v1.y + v1.z + v1.w;
                q += v0.x * v0.x + v0.y * v0.y + v0.z * v0.z + v0.w * v0.w
                   + v1.x * v1.x + v1.y * v1.y + v1.z * v1.z + v1.w * v1.w;
            }
        }
        s += __shfl_xor(s, 1); s += __shfl_xor(s, 2);
        q += __shfl_xor(q, 1); q += __shfl_xor(q, 2);
        float mean = s * (1.f / 384.f);
        float var = q * (1.f / 384.f) - mean * mean;
        stf = make_float2(mean, rsqrtf(var + 1e-5f));
    }

    float4 pa[2], pw[2];
    const float4 z4 = make_float4(0.f, 0.f, 0.f, 0.f);

    auto loadA = [&](int k0) {
        int k = k0 + q_s * 8;
        int m = bm + m_s;
        if (AMODE == 1) {
            int b = m >> 8, t = m & 255;
            int gh = t >> 3, gw = t & 7;
            int p1 = k >> 4, p2 = k & 15;
            const float* src = &gA[(size_t)b * 65536 + gh * 2048 + p1 * 128 + gw * 16 + p2];
            pa[0] = *(const float4*)src;
            pa[1] = *(const float4*)(src + 4);
        } else if (AMODE == 2) {  // flip-add
            if (m < M && k < K) {
                int b = m / LF, l = m - b * LF;
                const float* s1 = &A[(size_t)m * lda + k];
                const float* s2 = &A2[(size_t)(b * LF + (LF - 1 - l)) * lda + k];
                float4 x0 = *(const float4*)s1, x1 = *(const float4*)(s1 + 4);
                float4 y0 = *(const float4*)s2, y1 = *(const float4*)(s2 + 4);
                pa[0] = make_float4(x0.x + y0.x, x0.y + y0.y, x0.z + y0.z, x0.w + y0.w);
                pa[1] = make_float4(x1.x + y1.x, x1.y + y1.y, x1.z + y1.z, x1.w + y1.w);
            } else { pa[0] = z4; pa[1] = z4; }
        } else {  // AMODE 3: LayerNorm fused during staging
            if (m < M && k < K) {
                float4 r0 = *(const float4*)&A[(size_t)m * lda + k];
                float4 r1 = *(const float4*)&A[(size_t)m * lda + k + 4];
                float4 w0 = *(const float4*)&A2[k],  w1 = *(const float4*)&A2[k + 4];
                float4 b0 = *(const float4*)&pos[k], b1 = *(const float4*)&pos[k + 4];
                pa[0] = make_float4((r0.x - stf.x) * stf.y * w0.x + b0.x,
                                    (r0.y - stf.x) * stf.y * w0.y + b0.y,
                                    (r0.z - stf.x) * stf.y * w0.z + b0.z,
                                    (r0.w - stf.x) * stf.y * w0.w + b0.w);
                pa[1] = make_float4((r1.x - stf.x) * stf.y * w1.x + b1.x,
                                    (r1.y - stf.x) * stf.y * w1.y + b1.y,
                                    (r1.z - stf.x) * stf.y * w1.z + b1.z,
                                    (r1.w - stf.x) * stf.y * w1.w + b1.w);
            } else { pa[0] = z4; pa[1] = z4; }
        }
    };
    auto loadW = [&](int k0) {
        int k = k0 + q_s * 8;
        int n = bn + m_s;
        if (n < N && k < K) {
            pw[0] = *(const float4*)&W[(size_t)n * K + k];
            pw[1] = *(const float4*)&W[(size_t)n * K + k + 4];
        } else { pw[0] = z4; pw[1] = z4; }
    };
    auto cvt8 = [&](float4 a, float4 b) -> short8 {
        short8 r;
        r[0] = f2bf(a.x); r[1] = f2bf(a.y); r[2] = f2bf(a.z); r[3] = f2bf(a.w);
        r[4] = f2bf(b.x); r[5] = f2bf(b.y); r[6] = f2bf(b.z); r[7] = f2bf(b.w);
        return r;
    };

    loadA(kb);
    loadW(kb);

    int s = 0;
    for (int k0 = kb; k0 < ke; k0 += 32, ++s) {
        const int buf = (s & 1) * 2048;
        *(short8*)&Ab[buf + (q_s * 64 + m_s) * 8] = cvt8(pa[0], pa[1]);
        *(short8*)&Wb[buf + (q_s * 64 + m_s) * 8] = cvt8(pw[0], pw[1]);
        __syncthreads();
        if (k0 + 32 < ke) { loadA(k0 + 32); loadW(k0 + 32); }
        short8 af0 = *(const short8*)&Ab[buf + (qq * 64 + wm + lr) * 8];
        short8 af1 = *(const short8*)&Ab[buf + (qq * 64 + wm + 16 + lr) * 8];
        short8 wf0 = *(const short8*)&Wb[buf + (qq * 64 + wn + lr) * 8];
        short8 wf1 = *(const short8*)&Wb[buf + (qq * 64 + wn + 16 + lr) * 8];
        acc[0][0] = __builtin_amdgcn_mfma_f32_16x16x32_bf16(af0, wf0, acc[0][0], 0, 0, 0);
        acc[0][1] = __builtin_amdgcn_mfma_f32_16x16x32_bf16(af0, wf1, acc[0][1], 0, 0, 0);
        acc[1][0] = __builtin_amdgcn_mfma_f32_16x16x32_bf16(af1, wf0, acc[1][0], 0, 0, 0);
        acc[1][1] = __builtin_amdgcn_mfma_f32_16x16x32_bf16(af1, wf1, acc[1][1], 0, 0, 0);
    }

    #pragma unroll
    for (int mi = 0; mi < 2; ++mi) {
        #pragma unroll
        for (int ni = 0; ni < 2; ++ni) {
            int col = bn + wn + ni * 16 + lr;
            if (col >= N) continue;
            #pragma unroll
            for (int r = 0; r < 4; ++r) {
                int row = bm + wm + mi * 16 + qq * 4 + r;
                if (row >= M) continue;
                float v = acc[mi][ni][r];
                if (SMODE == 0) {
                    if (bias) v += bias[col];
                    Cout[(size_t)row * N + col] = v;
                } else if (SMODE == 3) {
                    int b = row >> 8, t = row & 255;
                    int l = (t < POSROW) ? t : t + 1;
                    v += bias[col] + pos[(size_t)l * DMODEL + col];
                    Cout[(size_t)(b * LF + l) * DMODEL + col] = v;
                } else {  // SMODE 4
                    atomicAdd(&Cout[(size_t)row * N + col], v);
                }
            }
        }
    }
}

template<int AMODE, int SMODE>
__global__ __launch_bounds__(256) void mgemm_k(
    const float* __restrict__ A, int lda,
    const float* __restrict__ W, const float* __restrict__ bias,
    float* __restrict__ Cout, int M, int N, int K, int KS,
    const float* __restrict__ gA, const float* __restrict__ A2,
    const float* __restrict__ pos)
{
    __shared__ __align__(16) short Ab[2 * 2048];
    __shared__ __align__(16) short Wb[2 * 2048];
    // XCD-aware bijective swizzle (nwg % 8 == 0 for all our grids)
    int nwg = gridDim.x * gridDim.y;
    int lin = blockIdx.x + blockIdx.y * gridDim.x;
    if ((nwg & 7) == 0) {
        int ch = nwg >> 3;
        lin = (lin & 7) * ch + (lin >> 3);
    }
    int bx = lin % gridDim.x;
    int by = lin / gridDim.x;
    int ntile = by / KS, ks = by % KS;
    int chunk = K / KS;
    mgemm_core<AMODE, SMODE>(A, lda, W, bias, Cout, M, N, K,
                             ks * chunk, ks * chunk + chunk, bx * 64, ntile * 64,
                             gA, A2, pos, Ab, Wb);
}

// ---------------------------------------------------------------------------
// Fused conv(K=4)+SiLU -> xproj MFMA. grid (17 m-tiles, NKC k-chunks, 2 br).
// Writes xc side-product; split-K partials atomicAdd into pre-zeroed xdb.
// ---------------------------------------------------------------------------
__global__ __launch_bounds__(256) void xp_k(
    const float* __restrict__ xz,
    const float* __restrict__ cwf, const float* __restrict__ cbf,
    const float* __restrict__ cwb, const float* __restrict__ cbb,
    const float* __restrict__ Wf, const float* __restrict__ Wb,
    float* __restrict__ xcf, float* __restrict__ xcb,
    float* __restrict__ xdbf, float* __restrict__ xdbb)
{
    __shared__ __align__(16) short Ash[2 * 2048];
    __shared__ __align__(16) short Wsh[2 * 2048];
    const int br = blockIdx.z;
    const int kcid = blockIdx.y;
    const float* cw = br ? cwb : cwf;
    const float* cbv = br ? cbb : cbf;
    const float* W  = br ? Wb  : Wf;
    float* xco      = br ? xcb : xcf;
    float* xdo      = br ? xdbb : xdbf;

    const int tid = threadIdx.x;
    const int m_s = tid >> 2, q_s = tid & 3;
    const int bm = blockIdx.x * 64;
    const int kb = kcid * 96;
    const int lane = tid & 63, wv = tid >> 6;
    const int wm = (wv >> 1) * 32, wn = (wv & 1) * 32;
    const int qq = lane >> 4, lr = lane & 15;
    const int m = bm + m_s;
    const bool mok = (m < MR);
    int b = 0, l = 0;
    if (mok) { b = m / LF; l = m - b * LF; }

    f32x4 acc[2][2];
    #pragma unroll
    for (int i = 0; i < 2; ++i)
        #pragma unroll
        for (int j = 0; j < 2; ++j)
            acc[i][j] = f32x4{0.f, 0.f, 0.f, 0.f};

    float a8[8];
    float4 pw0, pw1;
    const float4 z4 = make_float4(0.f, 0.f, 0.f, 0.f);

    auto loadA = [&](int k0) {
        int d0 = k0 + q_s * 8;
        if (mok) {
            float4 c0 = *(const float4*)&cbv[d0];
            float4 c1 = *(const float4*)&cbv[d0 + 4];
            a8[0] = c0.x; a8[1] = c0.y; a8[2] = c0.z; a8[3] = c0.w;
            a8[4] = c1.x; a8[5] = c1.y; a8[6] = c1.z; a8[7] = c1.w;
            float wreg[8][4];
            #pragma unroll
            for (int j = 0; j < 8; ++j)
                *(float4*)wreg[j] = *(const float4*)&cw[(d0 + j) * 4];
            #pragma unroll
            for (int kk = 0; kk < 4; ++kk) {
                int li = l - 3 + kk;
                if (li >= 0) {
                    int srow = br ? (b * LF + (LF - 1 - li)) : (b * LF + li);
                    const float* xp = &xz[(size_t)srow * 2 * DIN + d0];
                    float4 x0 = *(const float4*)xp, x1 = *(const float4*)(xp + 4);
                    a8[0] += x0.x * wreg[0][kk]; a8[1] += x0.y * wreg[1][kk];
                    a8[2] += x0.z * wreg[2][kk]; a8[3] += x0.w * wreg[3][kk];
                    a8[4] += x1.x * wreg[4][kk]; a8[5] += x1.y * wreg[5][kk];
                    a8[6] += x1.z * wreg[6][kk]; a8[7] += x1.w * wreg[7][kk];
                }
            }
            #pragma unroll
            for (int j = 0; j < 8; ++j) a8[j] = siluf(a8[j]);
        } else {
            #pragma unroll
            for (int j = 0; j < 8; ++j) a8[j] = 0.f;
        }
    };
    auto loadW = [&](int k0) {
        int k = k0 + q_s * 8;
        if (m_s < XDB) {
            pw0 = *(const float4*)&W[(size_t)m_s * DIN + k];
            pw1 = *(const float4*)&W[(size_t)m_s * DIN + k + 4];
        } else { pw0 = z4; pw1 = z4; }
    };
    auto cvt8f = [&]() -> short8 {
        short8 r;
        #pragma unroll
        for (int j = 0; j < 8; ++j) r[j] = f2bf(a8[j]);
        return r;
    };
    auto cvt8w = [&]() -> short8 {
        short8 r;
        r[0] = f2bf(pw0.x); r[1] = f2bf(pw0.y); r[2] = f2bf(pw0.z); r[3] = f2bf(pw0.w);
        r[4] = f2bf(pw1.x); r[5] = f2bf(pw1.y); r[6] = f2bf(pw1.z); r[7] = f2bf(pw1.w);
        return r;
    };

    loadA(kb);
    loadW(kb);

    #pragma unroll
    for (int s = 0; s < 3; ++s) {
        const int k0 = kb + s * 32;
        const int buf = (s & 1) * 2048;
        *(short8*)&Ash[buf + (q_s * 64 + m_s) * 8] = cvt8f();
        *(short8*)&Wsh[buf + (q_s * 64 + m_s) * 8] = cvt8w();
        if (mok) {  // side-product: materialize xc for the scan kernels
            int d0 = k0 + q_s * 8;
            *(float4*)&xco[(size_t)m * DIN + d0] =
                make_float4(a8[0], a8[1], a8[2], a8[3]);
            *(float4*)&xco[(size_t)m * DIN + d0 + 4] =
                make_float4(a8[4], a8[5], a8[6], a8[7]);
        }
        __syncthreads();
        if (s + 1 < 3) { loadA(k0 + 32); loadW(k0 + 32); }
        short8 af0 = *(const short8*)&Ash[buf + (qq * 64 + wm + lr) * 8];
        short8 af1 = *(const short8*)&Ash[buf + (qq * 64 + wm + 16 + lr) * 8];
        short8 wf0 = *(const short8*)&Wsh[buf + (qq * 64 + wn + lr) * 8];
        short8 wf1 = *(const short8*)&Wsh[buf + (qq * 64 + wn + 16 + lr) * 8];
        acc[0][0] = __builtin_amdgcn_mfma_f32_16x16x32_bf16(af0, wf0, acc[0][0], 0, 0, 0);
        acc[0][1] = __builtin_amdgcn_mfma_f32_16x16x32_bf16(af0, wf1, acc[0][1], 0, 0, 0);
        acc[1][0] = __builtin_amdgcn_mfma_f32_16x16x32_bf16(af1, wf0, acc[1][0], 0, 0, 0);
        acc[1][1] = __builtin_amdgcn_mfma_f32_16x16x32_bf16(af1, wf1, acc[1][1], 0, 0, 0);
        if (s + 1 < 3) __syncthreads();
    }

    #pragma unroll
    for (int mi = 0; mi < 2; ++mi) {
        #pragma unroll
        for (int ni = 0; ni < 2; ++ni) {
            int col = wn + ni * 16 + lr;
            if (col >= XDB) continue;
            #pragma unroll
            for (int r = 0; r < 4; ++r) {
                int row = bm + wm + mi * 16 + qq * 4 + r;
                if (row >= MR) continue;
                atomicAdd(&xdo[(size_t)row * XDB + col], acc[mi][ni][r]);
            }
        }
    }
}

// cls row: residual[b, 128, :] = cls + pos[128]
__global__ void cls_k(const float* __restrict__ cls, const float* __restrict__ pos,
                      float* __restrict__ residual) {
    int b = blockIdx.x, t = threadIdx.x;
    residual[(size_t)(b * LF + POSROW) * DMODEL + t] =
        cls[t] + pos[(size_t)POSROW * DMODEL + t];
}

// ---------------------------------------------------------------------------
// Chunked scan, SPLIT-NST: 2 paired lanes per d-column, 8 states each.
// Doubles grid parallelism (816 blocks) and halves per-thread serial work.
// block: 256 threads = 128 d x 2 halves; pair = adjacent lanes (shfl_xor 1).
// ---------------------------------------------------------------------------
__global__ __launch_bounds__(256) void scanA_k(
    const float* __restrict__ xcf, const float* __restrict__ xcb,
    const float* __restrict__ xdbf, const float* __restrict__ xdbb,
    const float* __restrict__ alf, const float* __restrict__ alb,
    const float* __restrict__ dwf, const float* __restrict__ dbf,
    const float* __restrict__ dwb, const float* __restrict__ dbb,
    float* __restrict__ hpart, float* __restrict__ sumd) {
    const int t = threadIdx.x;
    const int half = t & 1, dl = t >> 1;
    const int y = blockIdx.y;            // b*2+br
    const int b = y >> 1, br = y & 1;
    const int c = blockIdx.z;
    const int d = blockIdx.x * 128 + dl;
    const float* xc  = br ? xcb  : xcf;
    const float* xdb = br ? xdbb : xdbf;
    const float* Al  = br ? alb  : alf;
    const float* dw  = br ? dwb  : dwf;
    const float* dbi = br ? dbb  : dbf;

    float An[8];
    #pragma unroll
    for (int n = 0; n < 8; ++n)
        An[n] = -__expf(Al[(size_t)d * NST + half * 8 + n]);
    float wdt[DTR];
    #pragma unroll
    for (int k = 0; k < DTR; k += 4)
        *(float4*)&wdt[k] = *(const float4*)&dw[(size_t)d * DTR + k];
    float dbv = dbi[d];

    __shared__ float sXD[CL][DTR];
    __shared__ float sB[CL][NST];
    for (int idx = t; idx < CL * DTR; idx += 256) {
        int s0 = idx / DTR, j0 = idx - s0 * DTR;
        int l0 = c * CL + s0;
        sXD[s0][j0] = (l0 < LF) ? xdb[(size_t)(b * LF + l0) * XDB + j0] : 0.f;
    }
    {
        int s0 = t >> 4, j0 = t & 15;
        int l0 = c * CL + s0;
        sB[s0][j0] = (l0 < LF) ? xdb[(size_t)(b * LF + l0) * XDB + DTR + j0] : 0.f;
    }
    __syncthreads();

    float h[8] = {};
    float sdt = 0.f;
    #pragma unroll
    for (int s = 0; s < CL; ++s) {
        int l = c * CL + s;
        if (l < LF) {
            int row = b * LF + l;
            float dtv = dbv;
            #pragma unroll
            for (int k = 0; k < DTR; ++k) dtv += sXD[s][k] * wdt[k];
            dtv = softplusf(dtv);
            float xcv = xc[(size_t)row * DIN + d];
            sdt += dtv;
            float dtx = dtv * xcv;
            #pragma unroll
            for (int n = 0; n < 8; ++n)
                h[n] = __expf(dtv * An[n]) * h[n] + dtx * sB[s][half * 8 + n];
        }
    }
    size_t base = (size_t)(c * 8 + y) * NST;
    #pragma unroll
    for (int n = 0; n < 8; ++n)
        hpart[(base + half * 8 + n) * DIN + d] = h[n];
    if (half == 0) sumd[(size_t)(c * 8 + y) * DIN + d] = sdt;
}

__global__ __launch_bounds__(256) void scanC_k(
    const float* __restrict__ xcf, const float* __restrict__ xcb,
    const float* __restrict__ xdbf, const float* __restrict__ xdbb,
    const float* __restrict__ xz,
    const float* __restrict__ alf, const float* __restrict__ dpf,
    const float* __restrict__ alb, const float* __restrict__ dpb,
    const float* __restrict__ dwf, const float* __restrict__ dbf,
    const float* __restrict__ dwb, const float* __restrict__ dbb,
    const float* __restrict__ hpart, const float* __restrict__ sumd,
    float* __restrict__ yf, float* __restrict__ yb) {
    const int t = threadIdx.x;
    const int half = t & 1, dl = t >> 1;
    const int y = blockIdx.y;
    const int b = y >> 1, br = y & 1;
    const int c = blockIdx.z;
    const int d = blockIdx.x * 128 + dl;
    const float* xc  = br ? xcb  : xcf;
    const float* xdb = br ? xdbb : xdbf;
    const float* Al  = br ? alb  : alf;
    const float* Dpp = br ? dpb  : dpf;
    const float* dw  = br ? dwb  : dwf;
    const float* dbi = br ? dbb  : dbf;
    float* yo        = br ? yb   : yf;

    float An[8];
    #pragma unroll
    for (int n = 0; n < 8; ++n)
        An[n] = -__expf(Al[(size_t)d * NST + half * 8 + n]);
    float wdt[DTR];
    #pragma unroll
    for (int k = 0; k < DTR; k += 4)
        *(float4*)&wdt[k] = *(const float4*)&dw[(size_t)d * DTR + k];
    float dbv = dbi[d];
    float Dv = Dpp[d];

    __shared__ float sXD[CL][DTR];
    __shared__ float sB[CL][NST];
    __shared__ float sC[CL][NST];
    for (int idx = t; idx < CL * DTR; idx += 256) {
        int s0 = idx / DTR, j0 = idx - s0 * DTR;
        int l0 = c * CL + s0;
        sXD[s0][j0] = (l0 < LF) ? xdb[(size_t)(b * LF + l0) * XDB + j0] : 0.f;
    }
    {
        int s0 = t >> 4, j0 = t & 15;
        int l0 = c * CL + s0;
        size_t rb = (size_t)(b * LF + l0) * XDB + DTR;
        sB[s0][j0] = (l0 < LF) ? xdb[rb + j0] : 0.f;
        sC[s0][j0] = (l0 < LF) ? xdb[rb + NST + j0] : 0.f;
    }
    __syncthreads();

    // prefix-combine earlier chunks (this thread's 8 states)
    float h[8] = {};
    for (int j = 0; j < c; ++j) {
        float sd = sumd[(size_t)(j * 8 + y) * DIN + d];
        size_t bj = (size_t)(j * 8 + y) * NST;
        #pragma unroll
        for (int n = 0; n < 8; ++n)
            h[n] = __expf(An[n] * sd) * h[n] + hpart[(bj + half * 8 + n) * DIN + d];
    }

    #pragma unroll
    for (int s = 0; s < CL; ++s) {
        int l = c * CL + s;
        if (l < LF) {
            int row = b * LF + l;
            float dtv = dbv;
            #pragma unroll
            for (int k = 0; k < DTR; ++k) dtv += sXD[s][k] * wdt[k];
            dtv = softplusf(dtv);
            float xcv = xc[(size_t)row * DIN + d];
            int zl = br ? (LF - 1 - l) : l;
            float zv = xz[(size_t)(b * LF + zl) * (2 * DIN) + DIN + d];
            float dtx = dtv * xcv;
            float acc = 0.f;
            #pragma unroll
            for (int n = 0; n < 8; ++n) {
                h[n] = __expf(dtv * An[n]) * h[n] + dtx * sB[s][half * 8 + n];
                acc += h[n] * sC[s][half * 8 + n];
            }
            acc += __shfl_xor(acc, 1);   // combine the two halves' partial sums
            if (half == 0)
                yo[(size_t)row * DIN + d] = (acc + xcv * Dv) * siluf(zv);
        }
    }
}

// final LN(row POS) + command MLP + add -> f32 out
__global__ __launch_bounds__(384) void final_k(
    const float* __restrict__ residual,
    const float* __restrict__ lnw, const float* __restrict__ lnb,
    const float* __restrict__ sv, const float* __restrict__ act,
    const float* __restrict__ cw1, const float* __restrict__ cb1,
    const float* __restrict__ cw2, const float* __restrict__ cb2,
    float* __restrict__ out) {
    int b = blockIdx.x, t = threadIdx.x;
    const float* x = residual + (size_t)(b * LF + POSROW) * DMODEL;
    float v = x[t];
    float s = v, sq = v * v;
    #pragma unroll
    for (int o = 32; o > 0; o >>= 1) {
        s += __shfl_down(s, o);
        sq += __shfl_down(sq, o);
    }
    __shared__ float ls[6], lq[6], hid[DMODEL], cmdin[20];
    if ((t & 63) == 0) { ls[t >> 6] = s; lq[t >> 6] = sq; }
    if (t < 20) cmdin[t] = (t < 16) ? sv[b * 16 + t] : act[b * 4 + t - 16];
    __syncthreads();
    float S = 0.f, Q = 0.f;
    #pragma unroll
    for (int w = 0; w < 6; ++w) { S += ls[w]; Q += lq[w]; }
    float mean = S * (1.f / 384.f);
    float var = Q * (1.f / 384.f) - mean * mean;
    float rs = rsqrtf(var + 1e-5f);
    float vis = (v - mean) * rs * lnw[t] + lnb[t];
    float a1 = cb1[t];
    #pragma unroll
    for (int k = 0; k < 20; ++k) a1 += cmdin[k] * cw1[t * 20 + k];
    hid[t] = fmaxf(a1, 0.f);
    __syncthreads();
    float a2 = cb2[t];
    for (int k = 0; k < DMODEL; ++k) a2 += hid[k] * cw2[t * DMODEL + k];
    out[b * DMODEL + t] = vis + a2;
}

extern "C" void kernel_launch(void* const* d_in, const int* in_sizes, int n_in,
                              void* d_out, int out_size, void* d_ws, size_t ws_size,
                              hipStream_t stream) {
    const float* depth_seq = (const float*)d_in[0];
    const float* state_vec = (const float*)d_in[1];
    const float* action    = (const float*)d_in[2];
    const float* patch_w   = (const float*)d_in[3];
    const float* patch_b   = (const float*)d_in[4];
    const float* cls_token = (const float*)d_in[5];
    const float* pos_embed = (const float*)d_in[6];
    const float* ln_w      = (const float*)d_in[7];
    const float* ln_b      = (const float*)d_in[8];
    const float* in_proj_w = (const float*)d_in[9];
    const float* conv_w    = (const float*)d_in[10];
    const float* conv_b    = (const float*)d_in[11];
    const float* conv_wb   = (const float*)d_in[12];
    const float* conv_bb   = (const float*)d_in[13];
    const float* xproj_w   = (const float*)d_in[14];
    const float* xproj_wb  = (const float*)d_in[15];
    const float* dtproj_w  = (const float*)d_in[16];
    const float* dtproj_b  = (const float*)d_in[17];
    const float* dtproj_wb = (const float*)d_in[18];
    const float* dtproj_bb = (const float*)d_in[19];
    const float* A_log     = (const float*)d_in[20];
    const float* A_logb    = (const float*)d_in[21];
    const float* Dp        = (const float*)d_in[22];
    const float* Dpb       = (const float*)d_in[23];
    const float* out_w     = (const float*)d_in[24];
    const float* lnf_w     = (const float*)d_in[25];
    const float* lnf_b     = (const float*)d_in[26];
    const float* cw1       = (const float*)d_in[27];
    const float* cb1       = (const float*)d_in[28];
    const float* cw2       = (const float*)d_in[29];
    const float* cb2       = (const float*)d_in[30];

    float* ws = (float*)d_ws;
    size_t o = 0;
    float* residual = ws + o; o += (size_t)MR * DMODEL;
    float* xz       = ws + o; o += (size_t)MR * 2 * DIN;
    float* xcf      = ws + o; o += (size_t)MR * DIN;
    float* xcb      = ws + o; o += (size_t)MR * DIN;
    float* xdbf     = ws + o; o += (size_t)MR * XDB;   // adjacent pair:
    float* xdbb     = ws + o; o += (size_t)MR * XDB;   // single memset
    float* yfb      = ws + o; o += (size_t)MR * DIN;
    float* ybb      = ws + o; o += (size_t)MR * DIN;
    float* hpart    = ws + o; o += (size_t)NC * 8 * NST * DIN;
    float* sumd     = ws + o; o += (size_t)NC * 8 * DIN;
    (void)ws_size; (void)in_sizes; (void)n_in; (void)out_size;

    // patchify -> residual (bias + pos, cls gap), MFMA
    mgemm_k<1, 3><<<dim3(16, 6), 256, 0, stream>>>(
        nullptr, 0, patch_w, patch_b, residual, 1024, DMODEL, 256, 1,
        depth_seq, nullptr, pos_embed);
    cls_k<<<BB, DMODEL, 0, stream>>>(cls_token, pos_embed, residual);

    for (int i = 0; i < 4; ++i) {
        // in_proj with LN fused (stats computed in-block): 1028x384 @ 384x1536^T
        mgemm_k<3, 0><<<dim3(17, 24), 256, 0, stream>>>(
            residual, DMODEL, in_proj_w + (size_t)i * 2 * DIN * DMODEL, nullptr,
            xz, MR, 2 * DIN, DMODEL, 1,
            nullptr, ln_w + (size_t)i * DMODEL, ln_b + (size_t)i * DMODEL);
        // zero both xdb buffers (adjacent) for atomic split-K partials
        hipMemsetAsync(xdbf, 0, (size_t)2 * MR * XDB * sizeof(float), stream);
        // fused conv+SiLU + xproj (writes xcf/xcb + atomic xdb partials)
        xp_k<<<dim3(17, NKC, 2), 256, 0, stream>>>(
            xz, conv_w + (size_t)i * DIN * 4, conv_b + (size_t)i * DIN,
            conv_wb + (size_t)i * DIN * 4, conv_bb + (size_t)i * DIN,
            xproj_w + (size_t)i * XDB * DIN, xproj_wb + (size_t)i * XDB * DIN,
            xcf, xcb, xdbf, xdbb);
        // chunked scan with fused dt-projection (split-NST: 816 blocks each)
        scanA_k<<<dim3(6, 8, NC), 256, 0, stream>>>(
            xcf, xcb, xdbf, xdbb,
            A_log + (size_t)i * DIN * NST, A_logb + (size_t)i * DIN * NST,
            dtproj_w + (size_t)i * DIN * DTR, dtproj_b + (size_t)i * DIN,
            dtproj_wb + (size_t)i * DIN * DTR, dtproj_bb + (size_t)i * DIN,
            hpart, sumd);
        scanC_k<<<dim3(6, 8, NC), 256, 0, stream>>>(
            xcf, xcb, xdbf, xdbb, xz,
            A_log + (size_t)i * DIN * NST, Dp + (size_t)i * DIN,
            A_logb + (size_t)i * DIN * NST, Dpb + (size_t)i * DIN,
            dtproj_w + (size_t)i * DIN * DTR, dtproj_b + (size_t)i * DIN,
            dtproj_wb + (size_t)i * DIN * DTR, dtproj_bb + (size_t)i * DIN,
            hpart, sumd, yfb, ybb);
        // out_proj flip-add, split-K 4, atomicAdd accumulate into residual
        mgemm_k<2, 4><<<dim3(17, 6 * 4), 256, 0, stream>>>(
            yfb, DIN, out_w + (size_t)i * DMODEL * DIN, nullptr,
            residual, MR, DMODEL, DIN, 4, nullptr, ybb, nullptr);
    }

    final_k<<<BB, DMODEL, 0, stream>>>(
        residual, lnf_w, lnf_b, state_vec, action, cw1, cb1, cw2, cb2,
        (float*)d_out);
}

// Round 6
// 661.828 us; speedup vs baseline: 1.1967x; 1.0229x over previous
//
#include <hip/hip_runtime.h>
#include <hip/hip_bf16.h>
#include <math.h>

#define BB 4
#define LF 257      // NTOK+1
#define MR 1028     // BB*LF
#define DMODEL 384
#define DIN 768
#define NST 16
#define DTR 24
#define XDB 56      // DTR + 2*N
#define POSROW 128
#define CL 16       // scan chunk length
#define NC 17       // ceil(LF/CL)
#define NKC 8       // xp_k split-K chunks

typedef __attribute__((ext_vector_type(8))) short short8;
typedef __attribute__((ext_vector_type(4))) float f32x4;

__device__ __forceinline__ float siluf(float v) { return v / (1.f + __expf(-v)); }
__device__ __forceinline__ float softplusf(float v) {
    return (v > 20.f) ? v : log1pf(__expf(v));
}
__device__ __forceinline__ short f2bf(float f) {
    unsigned u = __builtin_bit_cast(unsigned, f);
    unsigned r = (u + 0x7FFFu + ((u >> 16) & 1u)) >> 16;
    return (short)r;
}

// ---------------------------------------------------------------------------
// bf16-MFMA GEMM core over K range [kb,ke): C[m,n] (+)= sum A[m,k]*W[n,k].
// 64x64 tile, 4 waves (2x2), each wave 2x2 mfma_f32_16x16x32_bf16.
// AMODE: 1 patch gather, 2 flip-add, 3 LN-fused (gA=stats(mean,rstd), A2=lnw,
//        pos=lnb)
// SMODE: 0 plain(+bias), 3 patchify store (bias+pos, cls gap), 4 atomicAdd
// ---------------------------------------------------------------------------
template<int AMODE, int SMODE>
__device__ __forceinline__ void mgemm_core(
    const float* __restrict__ A, int lda,
    const float* __restrict__ W,
    const float* __restrict__ bias,
    float* __restrict__ Cout, int M, int N, int K, int kb, int ke,
    int bm, int bn,
    const float* __restrict__ gA, const float* __restrict__ A2,
    const float* __restrict__ pos,
    short* __restrict__ Ab, short* __restrict__ Wb)
{
    const int tid = threadIdx.x;
    const int m_s = tid >> 2;
    const int q_s = tid & 3;
    const int lane = tid & 63;
    const int wv = tid >> 6;
    const int wm = (wv >> 1) * 32, wn = (wv & 1) * 32;
    const int qq = lane >> 4, lr = lane & 15;

    f32x4 acc[2][2];
    #pragma unroll
    for (int i = 0; i < 2; ++i)
        #pragma unroll
        for (int j = 0; j < 2; ++j)
            acc[i][j] = f32x4{0.f, 0.f, 0.f, 0.f};

    // AMODE 3: LN stats from the precomputed buffer (one lnstat pass per layer)
    float2 stf = make_float2(0.f, 0.f);
    if (AMODE == 3) {
        int m = bm + m_s;
        if (m < M) stf = ((const float2*)gA)[m];
    }

    float4 pa[2], pw[2];
    const float4 z4 = make_float4(0.f, 0.f, 0.f, 0.f);

    auto loadA = [&](int k0) {
        int k = k0 + q_s * 8;
        int m = bm + m_s;
        if (AMODE == 1) {
            int b = m >> 8, t = m & 255;
            int gh = t >> 3, gw = t & 7;
            int p1 = k >> 4, p2 = k & 15;
            const float* src = &gA[(size_t)b * 65536 + gh * 2048 + p1 * 128 + gw * 16 + p2];
            pa[0] = *(const float4*)src;
            pa[1] = *(const float4*)(src + 4);
        } else if (AMODE == 2) {  // flip-add
            if (m < M && k < K) {
                int b = m / LF, l = m - b * LF;
                const float* s1 = &A[(size_t)m * lda + k];
                const float* s2 = &A2[(size_t)(b * LF + (LF - 1 - l)) * lda + k];
                float4 x0 = *(const float4*)s1, x1 = *(const float4*)(s1 + 4);
                float4 y0 = *(const float4*)s2, y1 = *(const float4*)(s2 + 4);
                pa[0] = make_float4(x0.x + y0.x, x0.y + y0.y, x0.z + y0.z, x0.w + y0.w);
                pa[1] = make_float4(x1.x + y1.x, x1.y + y1.y, x1.z + y1.z, x1.w + y1.w);
            } else { pa[0] = z4; pa[1] = z4; }
        } else {  // AMODE 3: LayerNorm fused during staging
            if (m < M && k < K) {
                float4 r0 = *(const float4*)&A[(size_t)m * lda + k];
                float4 r1 = *(const float4*)&A[(size_t)m * lda + k + 4];
                float4 w0 = *(const float4*)&A2[k],  w1 = *(const float4*)&A2[k + 4];
                float4 b0 = *(const float4*)&pos[k], b1 = *(const float4*)&pos[k + 4];
                pa[0] = make_float4((r0.x - stf.x) * stf.y * w0.x + b0.x,
                                    (r0.y - stf.x) * stf.y * w0.y + b0.y,
                                    (r0.z - stf.x) * stf.y * w0.z + b0.z,
                                    (r0.w - stf.x) * stf.y * w0.w + b0.w);
                pa[1] = make_float4((r1.x - stf.x) * stf.y * w1.x + b1.x,
                                    (r1.y - stf.x) * stf.y * w1.y + b1.y,
                                    (r1.z - stf.x) * stf.y * w1.z + b1.z,
                                    (r1.w - stf.x) * stf.y * w1.w + b1.w);
            } else { pa[0] = z4; pa[1] = z4; }
        }
    };
    auto loadW = [&](int k0) {
        int k = k0 + q_s * 8;
        int n = bn + m_s;
        if (n < N && k < K) {
            pw[0] = *(const float4*)&W[(size_t)n * K + k];
            pw[1] = *(const float4*)&W[(size_t)n * K + k + 4];
        } else { pw[0] = z4; pw[1] = z4; }
    };
    auto cvt8 = [&](float4 a, float4 b) -> short8 {
        short8 r;
        r[0] = f2bf(a.x); r[1] = f2bf(a.y); r[2] = f2bf(a.z); r[3] = f2bf(a.w);
        r[4] = f2bf(b.x); r[5] = f2bf(b.y); r[6] = f2bf(b.z); r[7] = f2bf(b.w);
        return r;
    };

    loadA(kb);
    loadW(kb);

    int s = 0;
    for (int k0 = kb; k0 < ke; k0 += 32, ++s) {
        const int buf = (s & 1) * 2048;
        *(short8*)&Ab[buf + (q_s * 64 + m_s) * 8] = cvt8(pa[0], pa[1]);
        *(short8*)&Wb[buf + (q_s * 64 + m_s) * 8] = cvt8(pw[0], pw[1]);
        __syncthreads();
        if (k0 + 32 < ke) { loadA(k0 + 32); loadW(k0 + 32); }
        short8 af0 = *(const short8*)&Ab[buf + (qq * 64 + wm + lr) * 8];
        short8 af1 = *(const short8*)&Ab[buf + (qq * 64 + wm + 16 + lr) * 8];
        short8 wf0 = *(const short8*)&Wb[buf + (qq * 64 + wn + lr) * 8];
        short8 wf1 = *(const short8*)&Wb[buf + (qq * 64 + wn + 16 + lr) * 8];
        acc[0][0] = __builtin_amdgcn_mfma_f32_16x16x32_bf16(af0, wf0, acc[0][0], 0, 0, 0);
        acc[0][1] = __builtin_amdgcn_mfma_f32_16x16x32_bf16(af0, wf1, acc[0][1], 0, 0, 0);
        acc[1][0] = __builtin_amdgcn_mfma_f32_16x16x32_bf16(af1, wf0, acc[1][0], 0, 0, 0);
        acc[1][1] = __builtin_amdgcn_mfma_f32_16x16x32_bf16(af1, wf1, acc[1][1], 0, 0, 0);
    }

    #pragma unroll
    for (int mi = 0; mi < 2; ++mi) {
        #pragma unroll
        for (int ni = 0; ni < 2; ++ni) {
            int col = bn + wn + ni * 16 + lr;
            if (col >= N) continue;
            #pragma unroll
            for (int r = 0; r < 4; ++r) {
                int row = bm + wm + mi * 16 + qq * 4 + r;
                if (row >= M) continue;
                float v = acc[mi][ni][r];
                if (SMODE == 0) {
                    if (bias) v += bias[col];
                    Cout[(size_t)row * N + col] = v;
                } else if (SMODE == 3) {
                    int b = row >> 8, t = row & 255;
                    int l = (t < POSROW) ? t : t + 1;
                    v += bias[col] + pos[(size_t)l * DMODEL + col];
                    Cout[(size_t)(b * LF + l) * DMODEL + col] = v;
                } else {  // SMODE 4
                    atomicAdd(&Cout[(size_t)row * N + col], v);
                }
            }
        }
    }
}

template<int AMODE, int SMODE>
__global__ __launch_bounds__(256) void mgemm_k(
    const float* __restrict__ A, int lda,
    const float* __restrict__ W, const float* __restrict__ bias,
    float* __restrict__ Cout, int M, int N, int K, int KS,
    const float* __restrict__ gA, const float* __restrict__ A2,
    const float* __restrict__ pos,
    float* __restrict__ zbuf, int zcount)
{
    __shared__ __align__(16) short Ab[2 * 2048];
    __shared__ __align__(16) short Wb[2 * 2048];
    // fold downstream-buffer zeroing into this kernel (saves a memset dispatch;
    // kernel-boundary ordering guarantees completion before consumers' atomics)
    if (zbuf) {
        int nthr = gridDim.x * gridDim.y * 256;
        int gi = (blockIdx.x + blockIdx.y * gridDim.x) * 256 + threadIdx.x;
        for (int i = gi; i < zcount; i += nthr) zbuf[i] = 0.f;
    }
    // XCD-aware bijective swizzle (nwg % 8 == 0 for all our grids)
    int nwg = gridDim.x * gridDim.y;
    int lin = blockIdx.x + blockIdx.y * gridDim.x;
    if ((nwg & 7) == 0) {
        int ch = nwg >> 3;
        lin = (lin & 7) * ch + (lin >> 3);
    }
    int bx = lin % gridDim.x;
    int by = lin / gridDim.x;
    int ntile = by / KS, ks = by % KS;
    int chunk = K / KS;
    mgemm_core<AMODE, SMODE>(A, lda, W, bias, Cout, M, N, K,
                             ks * chunk, ks * chunk + chunk, bx * 64, ntile * 64,
                             gA, A2, pos, Ab, Wb);
}

// ---------------------------------------------------------------------------
// Fused conv(K=4)+SiLU -> xproj MFMA. grid (17 m-tiles, NKC k-chunks, 2 br).
// Writes xc side-product; split-K partials atomicAdd into pre-zeroed xdb.
// ---------------------------------------------------------------------------
__global__ __launch_bounds__(256) void xp_k(
    const float* __restrict__ xz,
    const float* __restrict__ cwf, const float* __restrict__ cbf,
    const float* __restrict__ cwb, const float* __restrict__ cbb,
    const float* __restrict__ Wf, const float* __restrict__ Wb,
    float* __restrict__ xcf, float* __restrict__ xcb,
    float* __restrict__ xdbf, float* __restrict__ xdbb)
{
    __shared__ __align__(16) short Ash[2 * 2048];
    __shared__ __align__(16) short Wsh[2 * 2048];
    const int br = blockIdx.z;
    const int kcid = blockIdx.y;
    const float* cw = br ? cwb : cwf;
    const float* cbv = br ? cbb : cbf;
    const float* W  = br ? Wb  : Wf;
    float* xco      = br ? xcb : xcf;
    float* xdo      = br ? xdbb : xdbf;

    const int tid = threadIdx.x;
    const int m_s = tid >> 2, q_s = tid & 3;
    const int bm = blockIdx.x * 64;
    const int kb = kcid * 96;
    const int lane = tid & 63, wv = tid >> 6;
    const int wm = (wv >> 1) * 32, wn = (wv & 1) * 32;
    const int qq = lane >> 4, lr = lane & 15;
    const int m = bm + m_s;
    const bool mok = (m < MR);
    int b = 0, l = 0;
    if (mok) { b = m / LF; l = m - b * LF; }

    f32x4 acc[2][2];
    #pragma unroll
    for (int i = 0; i < 2; ++i)
        #pragma unroll
        for (int j = 0; j < 2; ++j)
            acc[i][j] = f32x4{0.f, 0.f, 0.f, 0.f};

    float a8[8];
    float4 pw0, pw1;
    const float4 z4 = make_float4(0.f, 0.f, 0.f, 0.f);

    auto loadA = [&](int k0) {
        int d0 = k0 + q_s * 8;
        if (mok) {
            float4 c0 = *(const float4*)&cbv[d0];
            float4 c1 = *(const float4*)&cbv[d0 + 4];
            a8[0] = c0.x; a8[1] = c0.y; a8[2] = c0.z; a8[3] = c0.w;
            a8[4] = c1.x; a8[5] = c1.y; a8[6] = c1.z; a8[7] = c1.w;
            float wreg[8][4];
            #pragma unroll
            for (int j = 0; j < 8; ++j)
                *(float4*)wreg[j] = *(const float4*)&cw[(d0 + j) * 4];
            #pragma unroll
            for (int kk = 0; kk < 4; ++kk) {
                int li = l - 3 + kk;
                if (li >= 0) {
                    int srow = br ? (b * LF + (LF - 1 - li)) : (b * LF + li);
                    const float* xp = &xz[(size_t)srow * 2 * DIN + d0];
                    float4 x0 = *(const float4*)xp, x1 = *(const float4*)(xp + 4);
                    a8[0] += x0.x * wreg[0][kk]; a8[1] += x0.y * wreg[1][kk];
                    a8[2] += x0.z * wreg[2][kk]; a8[3] += x0.w * wreg[3][kk];
                    a8[4] += x1.x * wreg[4][kk]; a8[5] += x1.y * wreg[5][kk];
                    a8[6] += x1.z * wreg[6][kk]; a8[7] += x1.w * wreg[7][kk];
                }
            }
            #pragma unroll
            for (int j = 0; j < 8; ++j) a8[j] = siluf(a8[j]);
        } else {
            #pragma unroll
            for (int j = 0; j < 8; ++j) a8[j] = 0.f;
        }
    };
    auto loadW = [&](int k0) {
        int k = k0 + q_s * 8;
        if (m_s < XDB) {
            pw0 = *(const float4*)&W[(size_t)m_s * DIN + k];
            pw1 = *(const float4*)&W[(size_t)m_s * DIN + k + 4];
        } else { pw0 = z4; pw1 = z4; }
    };
    auto cvt8f = [&]() -> short8 {
        short8 r;
        #pragma unroll
        for (int j = 0; j < 8; ++j) r[j] = f2bf(a8[j]);
        return r;
    };
    auto cvt8w = [&]() -> short8 {
        short8 r;
        r[0] = f2bf(pw0.x); r[1] = f2bf(pw0.y); r[2] = f2bf(pw0.z); r[3] = f2bf(pw0.w);
        r[4] = f2bf(pw1.x); r[5] = f2bf(pw1.y); r[6] = f2bf(pw1.z); r[7] = f2bf(pw1.w);
        return r;
    };

    loadA(kb);
    loadW(kb);

    #pragma unroll
    for (int s = 0; s < 3; ++s) {
        const int k0 = kb + s * 32;
        const int buf = (s & 1) * 2048;
        *(short8*)&Ash[buf + (q_s * 64 + m_s) * 8] = cvt8f();
        *(short8*)&Wsh[buf + (q_s * 64 + m_s) * 8] = cvt8w();
        if (mok) {  // side-product: materialize xc for the scan kernels
            int d0 = k0 + q_s * 8;
            *(float4*)&xco[(size_t)m * DIN + d0] =
                make_float4(a8[0], a8[1], a8[2], a8[3]);
            *(float4*)&xco[(size_t)m * DIN + d0 + 4] =
                make_float4(a8[4], a8[5], a8[6], a8[7]);
        }
        __syncthreads();
        if (s + 1 < 3) { loadA(k0 + 32); loadW(k0 + 32); }
        short8 af0 = *(const short8*)&Ash[buf + (qq * 64 + wm + lr) * 8];
        short8 af1 = *(const short8*)&Ash[buf + (qq * 64 + wm + 16 + lr) * 8];
        short8 wf0 = *(const short8*)&Wsh[buf + (qq * 64 + wn + lr) * 8];
        short8 wf1 = *(const short8*)&Wsh[buf + (qq * 64 + wn + 16 + lr) * 8];
        acc[0][0] = __builtin_amdgcn_mfma_f32_16x16x32_bf16(af0, wf0, acc[0][0], 0, 0, 0);
        acc[0][1] = __builtin_amdgcn_mfma_f32_16x16x32_bf16(af0, wf1, acc[0][1], 0, 0, 0);
        acc[1][0] = __builtin_amdgcn_mfma_f32_16x16x32_bf16(af1, wf0, acc[1][0], 0, 0, 0);
        acc[1][1] = __builtin_amdgcn_mfma_f32_16x16x32_bf16(af1, wf1, acc[1][1], 0, 0, 0);
        if (s + 1 < 3) __syncthreads();
    }

    #pragma unroll
    for (int mi = 0; mi < 2; ++mi) {
        #pragma unroll
        for (int ni = 0; ni < 2; ++ni) {
            int col = wn + ni * 16 + lr;
            if (col >= XDB) continue;
            #pragma unroll
            for (int r = 0; r < 4; ++r) {
                int row = bm + wm + mi * 16 + qq * 4 + r;
                if (row >= MR) continue;
                atomicAdd(&xdo[(size_t)row * XDB + col], acc[mi][ni][r]);
            }
        }
    }
}

// cls row: residual[b, 128, :] = cls + pos[128]
__global__ void cls_k(const float* __restrict__ cls, const float* __restrict__ pos,
                      float* __restrict__ residual) {
    int b = blockIdx.x, t = threadIdx.x;
    residual[(size_t)(b * LF + POSROW) * DMODEL + t] =
        cls[t] + pos[(size_t)POSROW * DMODEL + t];
}

// row-wise layernorm STATS over 384 -> (mean, rstd) per row
__global__ __launch_bounds__(128) void lnstat_k(const float* __restrict__ X,
                                                float2* __restrict__ st) {
    int r = blockIdx.x;
    const float* x = X + (size_t)r * DMODEL;
    int t = threadIdx.x;
    float v0 = x[t], v1 = x[t + 128], v2 = x[t + 256];
    float s = v0 + v1 + v2;
    float sq = v0 * v0 + v1 * v1 + v2 * v2;
    #pragma unroll
    for (int o = 32; o > 0; o >>= 1) {
        s += __shfl_down(s, o);
        sq += __shfl_down(sq, o);
    }
    __shared__ float ls[2], lq[2];
    if ((t & 63) == 0) { ls[t >> 6] = s; lq[t >> 6] = sq; }
    __syncthreads();
    if (t == 0) {
        float S = ls[0] + ls[1], Q = lq[0] + lq[1];
        float mean = S * (1.f / 384.f);
        float var = Q * (1.f / 384.f) - mean * mean;
        st[r] = make_float2(mean, rsqrtf(var + 1e-5f));
    }
}

// ---------------------------------------------------------------------------
// Chunked scan, SPLIT-NST: 2 paired lanes per d-column, 8 states each.
// block: 256 threads = 128 d x 2 halves; pair = adjacent lanes (shfl_xor 1).
// ---------------------------------------------------------------------------
__global__ __launch_bounds__(256) void scanA_k(
    const float* __restrict__ xcf, const float* __restrict__ xcb,
    const float* __restrict__ xdbf, const float* __restrict__ xdbb,
    const float* __restrict__ alf, const float* __restrict__ alb,
    const float* __restrict__ dwf, const float* __restrict__ dbf,
    const float* __restrict__ dwb, const float* __restrict__ dbb,
    float* __restrict__ hpart, float* __restrict__ sumd) {
    const int t = threadIdx.x;
    const int half = t & 1, dl = t >> 1;
    const int y = blockIdx.y;            // b*2+br
    const int b = y >> 1, br = y & 1;
    const int c = blockIdx.z;
    const int d = blockIdx.x * 128 + dl;
    const float* xc  = br ? xcb  : xcf;
    const float* xdb = br ? xdbb : xdbf;
    const float* Al  = br ? alb  : alf;
    const float* dw  = br ? dwb  : dwf;
    const float* dbi = br ? dbb  : dbf;

    float An[8];
    #pragma unroll
    for (int n = 0; n < 8; ++n)
        An[n] = -__expf(Al[(size_t)d * NST + half * 8 + n]);
    float wdt[DTR];
    #pragma unroll
    for (int k = 0; k < DTR; k += 4)
        *(float4*)&wdt[k] = *(const float4*)&dw[(size_t)d * DTR + k];
    float dbv = dbi[d];

    __shared__ float sXD[CL][DTR];
    __shared__ float sB[CL][NST];
    for (int idx = t; idx < CL * DTR; idx += 256) {
        int s0 = idx / DTR, j0 = idx - s0 * DTR;
        int l0 = c * CL + s0;
        sXD[s0][j0] = (l0 < LF) ? xdb[(size_t)(b * LF + l0) * XDB + j0] : 0.f;
    }
    {
        int s0 = t >> 4, j0 = t & 15;
        int l0 = c * CL + s0;
        sB[s0][j0] = (l0 < LF) ? xdb[(size_t)(b * LF + l0) * XDB + DTR + j0] : 0.f;
    }
    __syncthreads();

    float h[8] = {};
    float sdt = 0.f;
    #pragma unroll
    for (int s = 0; s < CL; ++s) {
        int l = c * CL + s;
        if (l < LF) {
            int row = b * LF + l;
            float dtv = dbv;
            #pragma unroll
            for (int k = 0; k < DTR; ++k) dtv += sXD[s][k] * wdt[k];
            dtv = softplusf(dtv);
            float xcv = xc[(size_t)row * DIN + d];
            sdt += dtv;
            float dtx = dtv * xcv;
            #pragma unroll
            for (int n = 0; n < 8; ++n)
                h[n] = __expf(dtv * An[n]) * h[n] + dtx * sB[s][half * 8 + n];
        }
    }
    size_t base = (size_t)(c * 8 + y) * NST;
    #pragma unroll
    for (int n = 0; n < 8; ++n)
        hpart[(base + half * 8 + n) * DIN + d] = h[n];
    if (half == 0) sumd[(size_t)(c * 8 + y) * DIN + d] = sdt;
}

__global__ __launch_bounds__(256) void scanC_k(
    const float* __restrict__ xcf, const float* __restrict__ xcb,
    const float* __restrict__ xdbf, const float* __restrict__ xdbb,
    const float* __restrict__ xz,
    const float* __restrict__ alf, const float* __restrict__ dpf,
    const float* __restrict__ alb, const float* __restrict__ dpb,
    const float* __restrict__ dwf, const float* __restrict__ dbf,
    const float* __restrict__ dwb, const float* __restrict__ dbb,
    const float* __restrict__ hpart, const float* __restrict__ sumd,
    float* __restrict__ yf, float* __restrict__ yb) {
    const int t = threadIdx.x;
    const int half = t & 1, dl = t >> 1;
    const int y = blockIdx.y;
    const int b = y >> 1, br = y & 1;
    const int c = blockIdx.z;
    const int d = blockIdx.x * 128 + dl;
    const float* xc  = br ? xcb  : xcf;
    const float* xdb = br ? xdbb : xdbf;
    const float* Al  = br ? alb  : alf;
    const float* Dpp = br ? dpb  : dpf;
    const float* dw  = br ? dwb  : dwf;
    const float* dbi = br ? dbb  : dbf;
    float* yo        = br ? yb   : yf;

    float An[8];
    #pragma unroll
    for (int n = 0; n < 8; ++n)
        An[n] = -__expf(Al[(size_t)d * NST + half * 8 + n]);
    float wdt[DTR];
    #pragma unroll
    for (int k = 0; k < DTR; k += 4)
        *(float4*)&wdt[k] = *(const float4*)&dw[(size_t)d * DTR + k];
    float dbv = dbi[d];
    float Dv = Dpp[d];

    __shared__ float sXD[CL][DTR];
    __shared__ float sB[CL][NST];
    __shared__ float sC[CL][NST];
    for (int idx = t; idx < CL * DTR; idx += 256) {
        int s0 = idx / DTR, j0 = idx - s0 * DTR;
        int l0 = c * CL + s0;
        sXD[s0][j0] = (l0 < LF) ? xdb[(size_t)(b * LF + l0) * XDB + j0] : 0.f;
    }
    {
        int s0 = t >> 4, j0 = t & 15;
        int l0 = c * CL + s0;
        size_t rb = (size_t)(b * LF + l0) * XDB + DTR;
        sB[s0][j0] = (l0 < LF) ? xdb[rb + j0] : 0.f;
        sC[s0][j0] = (l0 < LF) ? xdb[rb + NST + j0] : 0.f;
    }
    __syncthreads();

    // prefix-combine earlier chunks (this thread's 8 states)
    float h[8] = {};
    for (int j = 0; j < c; ++j) {
        float sd = sumd[(size_t)(j * 8 + y) * DIN + d];
        size_t bj = (size_t)(j * 8 + y) * NST;
        #pragma unroll
        for (int n = 0; n < 8; ++n)
            h[n] = __expf(An[n] * sd) * h[n] + hpart[(bj + half * 8 + n) * DIN + d];
    }

    #pragma unroll
    for (int s = 0; s < CL; ++s) {
        int l = c * CL + s;
        if (l < LF) {
            int row = b * LF + l;
            float dtv = dbv;
            #pragma unroll
            for (int k = 0; k < DTR; ++k) dtv += sXD[s][k] * wdt[k];
            dtv = softplusf(dtv);
            float xcv = xc[(size_t)row * DIN + d];
            int zl = br ? (LF - 1 - l) : l;
            float zv = xz[(size_t)(b * LF + zl) * (2 * DIN) + DIN + d];
            float dtx = dtv * xcv;
            float acc = 0.f;
            #pragma unroll
            for (int n = 0; n < 8; ++n) {
                h[n] = __expf(dtv * An[n]) * h[n] + dtx * sB[s][half * 8 + n];
                acc += h[n] * sC[s][half * 8 + n];
            }
            acc += __shfl_xor(acc, 1);   // combine the two halves' partial sums
            if (half == 0)
                yo[(size_t)row * DIN + d] = (acc + xcv * Dv) * siluf(zv);
        }
    }
}

// final LN(row POS) + command MLP + add -> f32 out
__global__ __launch_bounds__(384) void final_k(
    const float* __restrict__ residual,
    const float* __restrict__ lnw, const float* __restrict__ lnb,
    const float* __restrict__ sv, const float* __restrict__ act,
    const float* __restrict__ cw1, const float* __restrict__ cb1,
    const float* __restrict__ cw2, const float* __restrict__ cb2,
    float* __restrict__ out) {
    int b = blockIdx.x, t = threadIdx.x;
    const float* x = residual + (size_t)(b * LF + POSROW) * DMODEL;
    float v = x[t];
    float s = v, sq = v * v;
    #pragma unroll
    for (int o = 32; o > 0; o >>= 1) {
        s += __shfl_down(s, o);
        sq += __shfl_down(sq, o);
    }
    __shared__ float ls[6], lq[6], hid[DMODEL], cmdin[20];
    if ((t & 63) == 0) { ls[t >> 6] = s; lq[t >> 6] = sq; }
    if (t < 20) cmdin[t] = (t < 16) ? sv[b * 16 + t] : act[b * 4 + t - 16];
    __syncthreads();
    float S = 0.f, Q = 0.f;
    #pragma unroll
    for (int w = 0; w < 6; ++w) { S += ls[w]; Q += lq[w]; }
    float mean = S * (1.f / 384.f);
    float var = Q * (1.f / 384.f) - mean * mean;
    float rs = rsqrtf(var + 1e-5f);
    float vis = (v - mean) * rs * lnw[t] + lnb[t];
    float a1 = cb1[t];
    #pragma unroll
    for (int k = 0; k < 20; ++k) a1 += cmdin[k] * cw1[t * 20 + k];
    hid[t] = fmaxf(a1, 0.f);
    __syncthreads();
    float a2 = cb2[t];
    for (int k = 0; k < DMODEL; ++k) a2 += hid[k] * cw2[t * DMODEL + k];
    out[b * DMODEL + t] = vis + a2;
}

extern "C" void kernel_launch(void* const* d_in, const int* in_sizes, int n_in,
                              void* d_out, int out_size, void* d_ws, size_t ws_size,
                              hipStream_t stream) {
    const float* depth_seq = (const float*)d_in[0];
    const float* state_vec = (const float*)d_in[1];
    const float* action    = (const float*)d_in[2];
    const float* patch_w   = (const float*)d_in[3];
    const float* patch_b   = (const float*)d_in[4];
    const float* cls_token = (const float*)d_in[5];
    const float* pos_embed = (const float*)d_in[6];
    const float* ln_w      = (const float*)d_in[7];
    const float* ln_b      = (const float*)d_in[8];
    const float* in_proj_w = (const float*)d_in[9];
    const float* conv_w    = (const float*)d_in[10];
    const float* conv_b    = (const float*)d_in[11];
    const float* conv_wb   = (const float*)d_in[12];
    const float* conv_bb   = (const float*)d_in[13];
    const float* xproj_w   = (const float*)d_in[14];
    const float* xproj_wb  = (const float*)d_in[15];
    const float* dtproj_w  = (const float*)d_in[16];
    const float* dtproj_b  = (const float*)d_in[17];
    const float* dtproj_wb = (const float*)d_in[18];
    const float* dtproj_bb = (const float*)d_in[19];
    const float* A_log     = (const float*)d_in[20];
    const float* A_logb    = (const float*)d_in[21];
    const float* Dp        = (const float*)d_in[22];
    const float* Dpb       = (const float*)d_in[23];
    const float* out_w     = (const float*)d_in[24];
    const float* lnf_w     = (const float*)d_in[25];
    const float* lnf_b     = (const float*)d_in[26];
    const float* cw1       = (const float*)d_in[27];
    const float* cb1       = (const float*)d_in[28];
    const float* cw2       = (const float*)d_in[29];
    const float* cb2       = (const float*)d_in[30];

    float* ws = (float*)d_ws;
    size_t o = 0;
    float* residual = ws + o; o += (size_t)MR * DMODEL;
    float* xz       = ws + o; o += (size_t)MR * 2 * DIN;
    float* xcf      = ws + o; o += (size_t)MR * DIN;
    float* xcb      = ws + o; o += (size_t)MR * DIN;
    float* xdbf     = ws + o; o += (size_t)MR * XDB;   // adjacent pair:
    float* xdbb     = ws + o; o += (size_t)MR * XDB;   // zeroed by in_proj
    float* yfb      = ws + o; o += (size_t)MR * DIN;
    float* ybb      = ws + o; o += (size_t)MR * DIN;
    float* hpart    = ws + o; o += (size_t)NC * 8 * NST * DIN;
    float* sumd     = ws + o; o += (size_t)NC * 8 * DIN;
    float2* stats   = (float2*)(ws + o); o += (size_t)MR * 2;
    (void)ws_size; (void)in_sizes; (void)n_in; (void)out_size;

    // patchify -> residual (bias + pos, cls gap), MFMA
    mgemm_k<1, 3><<<dim3(16, 6), 256, 0, stream>>>(
        nullptr, 0, patch_w, patch_b, residual, 1024, DMODEL, 256, 1,
        depth_seq, nullptr, pos_embed, nullptr, 0);
    cls_k<<<BB, DMODEL, 0, stream>>>(cls_token, pos_embed, residual);

    for (int i = 0; i < 4; ++i) {
        // LN stats: one pass per layer (proven R0 flow)
        lnstat_k<<<MR, 128, 0, stream>>>(residual, stats);
        // in_proj with fused LN (stats from buffer); also zeroes xdb for xp_k
        mgemm_k<3, 0><<<dim3(17, 24), 256, 0, stream>>>(
            residual, DMODEL, in_proj_w + (size_t)i * 2 * DIN * DMODEL, nullptr,
            xz, MR, 2 * DIN, DMODEL, 1,
            (const float*)stats, ln_w + (size_t)i * DMODEL, ln_b + (size_t)i * DMODEL,
            xdbf, 2 * MR * XDB);
        // fused conv+SiLU + xproj (writes xcf/xcb + atomic xdb partials)
        xp_k<<<dim3(17, NKC, 2), 256, 0, stream>>>(
            xz, conv_w + (size_t)i * DIN * 4, conv_b + (size_t)i * DIN,
            conv_wb + (size_t)i * DIN * 4, conv_bb + (size_t)i * DIN,
            xproj_w + (size_t)i * XDB * DIN, xproj_wb + (size_t)i * XDB * DIN,
            xcf, xcb, xdbf, xdbb);
        // chunked scan with fused dt-projection (split-NST: 816 blocks each)
        scanA_k<<<dim3(6, 8, NC), 256, 0, stream>>>(
            xcf, xcb, xdbf, xdbb,
            A_log + (size_t)i * DIN * NST, A_logb + (size_t)i * DIN * NST,
            dtproj_w + (size_t)i * DIN * DTR, dtproj_b + (size_t)i * DIN,
            dtproj_wb + (size_t)i * DIN * DTR, dtproj_bb + (size_t)i * DIN,
            hpart, sumd);
        scanC_k<<<dim3(6, 8, NC), 256, 0, stream>>>(
            xcf, xcb, xdbf, xdbb, xz,
            A_log + (size_t)i * DIN * NST, Dp + (size_t)i * DIN,
            A_logb + (size_t)i * DIN * NST, Dpb + (size_t)i * DIN,
            dtproj_w + (size_t)i * DIN * DTR, dtproj_b + (size_t)i * DIN,
            dtproj_wb + (size_t)i * DIN * DTR, dtproj_bb + (size_t)i * DIN,
            hpart, sumd, yfb, ybb);
        // out_proj flip-add, split-K 4, atomicAdd accumulate into residual
        mgemm_k<2, 4><<<dim3(17, 6 * 4), 256, 0, stream>>>(
            yfb, DIN, out_w + (size_t)i * DMODEL * DIN, nullptr,
            residual, MR, DMODEL, DIN, 4, nullptr, ybb, nullptr, nullptr, 0);
    }

    final_k<<<BB, DMODEL, 0, stream>>>(
        residual, lnf_w, lnf_b, state_vec, action, cw1, cb1, cw2, cb2,
        (float*)d_out);
}

// Round 7
// 573.863 us; speedup vs baseline: 1.3802x; 1.1533x over previous
//
#include <hip/hip_runtime.h>
#include <hip/hip_bf16.h>
#include <math.h>

#define BB 4
#define LF 257      // NTOK+1
#define MR 1028     // BB*LF
#define DMODEL 384
#define DIN 768
#define NST 16
#define DTR 24
#define XDB 56      // DTR + 2*N
#define POSROW 128
#define CL 16       // scan chunk length
#define NC 17       // ceil(LF/CL)
#define NKC 8       // xp_k split-K chunks

typedef __attribute__((ext_vector_type(8))) short short8;
typedef __attribute__((ext_vector_type(4))) float f32x4;

__device__ __forceinline__ float siluf(float v) { return v / (1.f + __expf(-v)); }
__device__ __forceinline__ float softplusf(float v) {
    return (v > 20.f) ? v : log1pf(__expf(v));
}
__device__ __forceinline__ short f2bf(float f) {
    unsigned u = __builtin_bit_cast(unsigned, f);
    unsigned r = (u + 0x7FFFu + ((u >> 16) & 1u)) >> 16;
    return (short)r;
}

// ---------------------------------------------------------------------------
// bf16-MFMA GEMM core over K range [kb,ke): C[m,n] (+)= sum A[m,k]*W[n,k].
// 64x64 tile, 4 waves (2x2). K-STEP 64: per step each thread stages 16 floats
// per matrix (4x float4, independent loads -> one latency), one barrier,
// 8 ds_read_b128 + 8 MFMA per wave. Halves the serialized step count vs K32.
// kgroup g in [0,8) holds k in [8g, 8g+8); thread (m_s,q_s) stores groups
// 2q_s and 2q_s+1; MFMA reads kg = kh*4 + qq for K-half kh.
// AMODE: 1 patch gather, 2 flip-add, 3 LN-fused (gA=stats(mean,rstd))
// SMODE: 0 plain(+bias), 3 patchify store (bias+pos, cls gap), 4 atomicAdd
// Requires kb, ke multiples of 64 (384, 256, 192-chunks all qualify).
// ---------------------------------------------------------------------------
template<int AMODE, int SMODE>
__device__ __forceinline__ void mgemm_core(
    const float* __restrict__ A, int lda,
    const float* __restrict__ W,
    const float* __restrict__ bias,
    float* __restrict__ Cout, int M, int N, int K, int kb, int ke,
    int bm, int bn,
    const float* __restrict__ gA, const float* __restrict__ A2,
    const float* __restrict__ pos,
    short* __restrict__ Ab, short* __restrict__ Wb)
{
    const int tid = threadIdx.x;
    const int m_s = tid >> 2;
    const int q_s = tid & 3;
    const int lane = tid & 63;
    const int wv = tid >> 6;
    const int wm = (wv >> 1) * 32, wn = (wv & 1) * 32;
    const int qq = lane >> 4, lr = lane & 15;

    f32x4 acc[2][2];
    #pragma unroll
    for (int i = 0; i < 2; ++i)
        #pragma unroll
        for (int j = 0; j < 2; ++j)
            acc[i][j] = f32x4{0.f, 0.f, 0.f, 0.f};

    // AMODE 3: LN stats from the precomputed buffer (one lnstat pass per layer)
    float2 stf = make_float2(0.f, 0.f);
    if (AMODE == 3) {
        int m = bm + m_s;
        if (m < M) stf = ((const float2*)gA)[m];
    }

    float4 pa[4], pw[4];
    const float4 z4 = make_float4(0.f, 0.f, 0.f, 0.f);

    auto loadA = [&](int k0) {
        int k = k0 + q_s * 16;
        int m = bm + m_s;
        if (AMODE == 1) {
            int b = m >> 8, t = m & 255;
            int gh = t >> 3, gw = t & 7;
            int p1 = k >> 4, p2 = k & 15;   // p2 == 0 for k0 % 64 == 0
            const float* src = &gA[(size_t)b * 65536 + gh * 2048 + p1 * 128 + gw * 16 + p2];
            pa[0] = ((const float4*)src)[0];
            pa[1] = ((const float4*)src)[1];
            pa[2] = ((const float4*)src)[2];
            pa[3] = ((const float4*)src)[3];
        } else if (AMODE == 2) {  // flip-add
            if (m < M && k < K) {
                int b = m / LF, l = m - b * LF;
                const float4* s1 = (const float4*)&A[(size_t)m * lda + k];
                const float4* s2 = (const float4*)&A2[(size_t)(b * LF + (LF - 1 - l)) * lda + k];
                #pragma unroll
                for (int i = 0; i < 4; ++i) {
                    float4 x = s1[i], y = s2[i];
                    pa[i] = make_float4(x.x + y.x, x.y + y.y, x.z + y.z, x.w + y.w);
                }
            } else { pa[0] = z4; pa[1] = z4; pa[2] = z4; pa[3] = z4; }
        } else {  // AMODE 3: LayerNorm fused during staging
            if (m < M && k < K) {
                const float4* rr = (const float4*)&A[(size_t)m * lda + k];
                const float4* ww = (const float4*)&A2[k];
                const float4* bb = (const float4*)&pos[k];
                #pragma unroll
                for (int i = 0; i < 4; ++i) {
                    float4 r = rr[i], w = ww[i], b0 = bb[i];
                    pa[i] = make_float4((r.x - stf.x) * stf.y * w.x + b0.x,
                                        (r.y - stf.x) * stf.y * w.y + b0.y,
                                        (r.z - stf.x) * stf.y * w.z + b0.z,
                                        (r.w - stf.x) * stf.y * w.w + b0.w);
                }
            } else { pa[0] = z4; pa[1] = z4; pa[2] = z4; pa[3] = z4; }
        }
    };
    auto loadW = [&](int k0) {
        int k = k0 + q_s * 16;
        int n = bn + m_s;
        if (n < N && k < K) {
            const float4* src = (const float4*)&W[(size_t)n * K + k];
            pw[0] = src[0]; pw[1] = src[1]; pw[2] = src[2]; pw[3] = src[3];
        } else { pw[0] = z4; pw[1] = z4; pw[2] = z4; pw[3] = z4; }
    };
    auto cvt8 = [&](float4 a, float4 b) -> short8 {
        short8 r;
        r[0] = f2bf(a.x); r[1] = f2bf(a.y); r[2] = f2bf(a.z); r[3] = f2bf(a.w);
        r[4] = f2bf(b.x); r[5] = f2bf(b.y); r[6] = f2bf(b.z); r[7] = f2bf(b.w);
        return r;
    };

    loadA(kb);
    loadW(kb);

    int s = 0;
    for (int k0 = kb; k0 < ke; k0 += 64, ++s) {
        const int buf = (s & 1) * 4096;
        *(short8*)&Ab[buf + ((2 * q_s) * 64 + m_s) * 8]     = cvt8(pa[0], pa[1]);
        *(short8*)&Ab[buf + ((2 * q_s + 1) * 64 + m_s) * 8] = cvt8(pa[2], pa[3]);
        *(short8*)&Wb[buf + ((2 * q_s) * 64 + m_s) * 8]     = cvt8(pw[0], pw[1]);
        *(short8*)&Wb[buf + ((2 * q_s + 1) * 64 + m_s) * 8] = cvt8(pw[2], pw[3]);
        __syncthreads();
        if (k0 + 64 < ke) { loadA(k0 + 64); loadW(k0 + 64); }
        #pragma unroll
        for (int kh = 0; kh < 2; ++kh) {
            const int kg = kh * 4 + qq;
            short8 af0 = *(const short8*)&Ab[buf + (kg * 64 + wm + lr) * 8];
            short8 af1 = *(const short8*)&Ab[buf + (kg * 64 + wm + 16 + lr) * 8];
            short8 wf0 = *(const short8*)&Wb[buf + (kg * 64 + wn + lr) * 8];
            short8 wf1 = *(const short8*)&Wb[buf + (kg * 64 + wn + 16 + lr) * 8];
            acc[0][0] = __builtin_amdgcn_mfma_f32_16x16x32_bf16(af0, wf0, acc[0][0], 0, 0, 0);
            acc[0][1] = __builtin_amdgcn_mfma_f32_16x16x32_bf16(af0, wf1, acc[0][1], 0, 0, 0);
            acc[1][0] = __builtin_amdgcn_mfma_f32_16x16x32_bf16(af1, wf0, acc[1][0], 0, 0, 0);
            acc[1][1] = __builtin_amdgcn_mfma_f32_16x16x32_bf16(af1, wf1, acc[1][1], 0, 0, 0);
        }
    }

    #pragma unroll
    for (int mi = 0; mi < 2; ++mi) {
        #pragma unroll
        for (int ni = 0; ni < 2; ++ni) {
            int col = bn + wn + ni * 16 + lr;
            if (col >= N) continue;
            #pragma unroll
            for (int r = 0; r < 4; ++r) {
                int row = bm + wm + mi * 16 + qq * 4 + r;
                if (row >= M) continue;
                float v = acc[mi][ni][r];
                if (SMODE == 0) {
                    if (bias) v += bias[col];
                    Cout[(size_t)row * N + col] = v;
                } else if (SMODE == 3) {
                    int b = row >> 8, t = row & 255;
                    int l = (t < POSROW) ? t : t + 1;
                    v += bias[col] + pos[(size_t)l * DMODEL + col];
                    Cout[(size_t)(b * LF + l) * DMODEL + col] = v;
                } else {  // SMODE 4
                    atomicAdd(&Cout[(size_t)row * N + col], v);
                }
            }
        }
    }
}

template<int AMODE, int SMODE>
__global__ __launch_bounds__(256) void mgemm_k(
    const float* __restrict__ A, int lda,
    const float* __restrict__ W, const float* __restrict__ bias,
    float* __restrict__ Cout, int M, int N, int K, int KS,
    const float* __restrict__ gA, const float* __restrict__ A2,
    const float* __restrict__ pos,
    float* __restrict__ zbuf, int zcount)
{
    __shared__ __align__(16) short Ab[2 * 4096];
    __shared__ __align__(16) short Wb[2 * 4096];
    // fold downstream-buffer zeroing into this kernel (saves a memset dispatch;
    // kernel-boundary ordering guarantees completion before consumers' atomics)
    if (zbuf) {
        int nthr = gridDim.x * gridDim.y * 256;
        int gi = (blockIdx.x + blockIdx.y * gridDim.x) * 256 + threadIdx.x;
        for (int i = gi; i < zcount; i += nthr) zbuf[i] = 0.f;
    }
    // XCD-aware bijective swizzle (nwg % 8 == 0 for all our grids)
    int nwg = gridDim.x * gridDim.y;
    int lin = blockIdx.x + blockIdx.y * gridDim.x;
    if ((nwg & 7) == 0) {
        int ch = nwg >> 3;
        lin = (lin & 7) * ch + (lin >> 3);
    }
    int bx = lin % gridDim.x;
    int by = lin / gridDim.x;
    int ntile = by / KS, ks = by % KS;
    int chunk = K / KS;
    mgemm_core<AMODE, SMODE>(A, lda, W, bias, Cout, M, N, K,
                             ks * chunk, ks * chunk + chunk, bx * 64, ntile * 64,
                             gA, A2, pos, Ab, Wb);
}

// ---------------------------------------------------------------------------
// Fused conv(K=4)+SiLU -> xproj MFMA. grid (17 m-tiles, NKC k-chunks, 2 br).
// Writes xc side-product; split-K partials atomicAdd into pre-zeroed xdb.
// ---------------------------------------------------------------------------
__global__ __launch_bounds__(256) void xp_k(
    const float* __restrict__ xz,
    const float* __restrict__ cwf, const float* __restrict__ cbf,
    const float* __restrict__ cwb, const float* __restrict__ cbb,
    const float* __restrict__ Wf, const float* __restrict__ Wb,
    float* __restrict__ xcf, float* __restrict__ xcb,
    float* __restrict__ xdbf, float* __restrict__ xdbb)
{
    __shared__ __align__(16) short Ash[2 * 2048];
    __shared__ __align__(16) short Wsh[2 * 2048];
    const int br = blockIdx.z;
    const int kcid = blockIdx.y;
    const float* cw = br ? cwb : cwf;
    const float* cbv = br ? cbb : cbf;
    const float* W  = br ? Wb  : Wf;
    float* xco      = br ? xcb : xcf;
    float* xdo      = br ? xdbb : xdbf;

    const int tid = threadIdx.x;
    const int m_s = tid >> 2, q_s = tid & 3;
    const int bm = blockIdx.x * 64;
    const int kb = kcid * 96;
    const int lane = tid & 63, wv = tid >> 6;
    const int wm = (wv >> 1) * 32, wn = (wv & 1) * 32;
    const int qq = lane >> 4, lr = lane & 15;
    const int m = bm + m_s;
    const bool mok = (m < MR);
    int b = 0, l = 0;
    if (mok) { b = m / LF; l = m - b * LF; }

    f32x4 acc[2][2];
    #pragma unroll
    for (int i = 0; i < 2; ++i)
        #pragma unroll
        for (int j = 0; j < 2; ++j)
            acc[i][j] = f32x4{0.f, 0.f, 0.f, 0.f};

    float a8[8];
    float4 pw0, pw1;
    const float4 z4 = make_float4(0.f, 0.f, 0.f, 0.f);

    auto loadA = [&](int k0) {
        int d0 = k0 + q_s * 8;
        if (mok) {
            float4 c0 = *(const float4*)&cbv[d0];
            float4 c1 = *(const float4*)&cbv[d0 + 4];
            a8[0] = c0.x; a8[1] = c0.y; a8[2] = c0.z; a8[3] = c0.w;
            a8[4] = c1.x; a8[5] = c1.y; a8[6] = c1.z; a8[7] = c1.w;
            float wreg[8][4];
            #pragma unroll
            for (int j = 0; j < 8; ++j)
                *(float4*)wreg[j] = *(const float4*)&cw[(d0 + j) * 4];
            #pragma unroll
            for (int kk = 0; kk < 4; ++kk) {
                int li = l - 3 + kk;
                if (li >= 0) {
                    int srow = br ? (b * LF + (LF - 1 - li)) : (b * LF + li);
                    const float* xp = &xz[(size_t)srow * 2 * DIN + d0];
                    float4 x0 = *(const float4*)xp, x1 = *(const float4*)(xp + 4);
                    a8[0] += x0.x * wreg[0][kk]; a8[1] += x0.y * wreg[1][kk];
                    a8[2] += x0.z * wreg[2][kk]; a8[3] += x0.w * wreg[3][kk];
                    a8[4] += x1.x * wreg[4][kk]; a8[5] += x1.y * wreg[5][kk];
                    a8[6] += x1.z * wreg[6][kk]; a8[7] += x1.w * wreg[7][kk];
                }
            }
            #pragma unroll
            for (int j = 0; j < 8; ++j) a8[j] = siluf(a8[j]);
        } else {
            #pragma unroll
            for (int j = 0; j < 8; ++j) a8[j] = 0.f;
        }
    };
    auto loadW = [&](int k0) {
        int k = k0 + q_s * 8;
        if (m_s < XDB) {
            pw0 = *(const float4*)&W[(size_t)m_s * DIN + k];
            pw1 = *(const float4*)&W[(size_t)m_s * DIN + k + 4];
        } else { pw0 = z4; pw1 = z4; }
    };
    auto cvt8f = [&]() -> short8 {
        short8 r;
        #pragma unroll
        for (int j = 0; j < 8; ++j) r[j] = f2bf(a8[j]);
        return r;
    };
    auto cvt8w = [&]() -> short8 {
        short8 r;
        r[0] = f2bf(pw0.x); r[1] = f2bf(pw0.y); r[2] = f2bf(pw0.z); r[3] = f2bf(pw0.w);
        r[4] = f2bf(pw1.x); r[5] = f2bf(pw1.y); r[6] = f2bf(pw1.z); r[7] = f2bf(pw1.w);
        return r;
    };

    loadA(kb);
    loadW(kb);

    #pragma unroll
    for (int s = 0; s < 3; ++s) {
        const int k0 = kb + s * 32;
        const int buf = (s & 1) * 2048;
        *(short8*)&Ash[buf + (q_s * 64 + m_s) * 8] = cvt8f();
        *(short8*)&Wsh[buf + (q_s * 64 + m_s) * 8] = cvt8w();
        if (mok) {  // side-product: materialize xc for the scan kernels
            int d0 = k0 + q_s * 8;
            *(float4*)&xco[(size_t)m * DIN + d0] =
                make_float4(a8[0], a8[1], a8[2], a8[3]);
            *(float4*)&xco[(size_t)m * DIN + d0 + 4] =
                make_float4(a8[4], a8[5], a8[6], a8[7]);
        }
        __syncthreads();
        if (s + 1 < 3) { loadA(k0 + 32); loadW(k0 + 32); }
        short8 af0 = *(const short8*)&Ash[buf + (qq * 64 + wm + lr) * 8];
        short8 af1 = *(const short8*)&Ash[buf + (qq * 64 + wm + 16 + lr) * 8];
        short8 wf0 = *(const short8*)&Wsh[buf + (qq * 64 + wn + lr) * 8];
        short8 wf1 = *(const short8*)&Wsh[buf + (qq * 64 + wn + 16 + lr) * 8];
        acc[0][0] = __builtin_amdgcn_mfma_f32_16x16x32_bf16(af0, wf0, acc[0][0], 0, 0, 0);
        acc[0][1] = __builtin_amdgcn_mfma_f32_16x16x32_bf16(af0, wf1, acc[0][1], 0, 0, 0);
        acc[1][0] = __builtin_amdgcn_mfma_f32_16x16x32_bf16(af1, wf0, acc[1][0], 0, 0, 0);
        acc[1][1] = __builtin_amdgcn_mfma_f32_16x16x32_bf16(af1, wf1, acc[1][1], 0, 0, 0);
        if (s + 1 < 3) __syncthreads();
    }

    #pragma unroll
    for (int mi = 0; mi < 2; ++mi) {
        #pragma unroll
        for (int ni = 0; ni < 2; ++ni) {
            int col = wn + ni * 16 + lr;
            if (col >= XDB) continue;
            #pragma unroll
            for (int r = 0; r < 4; ++r) {
                int row = bm + wm + mi * 16 + qq * 4 + r;
                if (row >= MR) continue;
                atomicAdd(&xdo[(size_t)row * XDB + col], acc[mi][ni][r]);
            }
        }
    }
}

// cls row: residual[b, 128, :] = cls + pos[128]
__global__ void cls_k(const float* __restrict__ cls, const float* __restrict__ pos,
                      float* __restrict__ residual) {
    int b = blockIdx.x, t = threadIdx.x;
    residual[(size_t)(b * LF + POSROW) * DMODEL + t] =
        cls[t] + pos[(size_t)POSROW * DMODEL + t];
}

// row-wise layernorm STATS over 384 -> (mean, rstd) per row
__global__ __launch_bounds__(128) void lnstat_k(const float* __restrict__ X,
                                                float2* __restrict__ st) {
    int r = blockIdx.x;
    const float* x = X + (size_t)r * DMODEL;
    int t = threadIdx.x;
    float v0 = x[t], v1 = x[t + 128], v2 = x[t + 256];
    float s = v0 + v1 + v2;
    float sq = v0 * v0 + v1 * v1 + v2 * v2;
    #pragma unroll
    for (int o = 32; o > 0; o >>= 1) {
        s += __shfl_down(s, o);
        sq += __shfl_down(sq, o);
    }
    __shared__ float ls[2], lq[2];
    if ((t & 63) == 0) { ls[t >> 6] = s; lq[t >> 6] = sq; }
    __syncthreads();
    if (t == 0) {
        float S = ls[0] + ls[1], Q = lq[0] + lq[1];
        float mean = S * (1.f / 384.f);
        float var = Q * (1.f / 384.f) - mean * mean;
        st[r] = make_float2(mean, rsqrtf(var + 1e-5f));
    }
}

// ---------------------------------------------------------------------------
// Chunked scan, SPLIT-NST: 2 paired lanes per d-column, 8 states each.
// xcv/zv batch-prefetched into registers BEFORE the serial loop (16
// independent coalesced loads -> one latency instead of 16 exposed).
// ---------------------------------------------------------------------------
__global__ __launch_bounds__(256) void scanA_k(
    const float* __restrict__ xcf, const float* __restrict__ xcb,
    const float* __restrict__ xdbf, const float* __restrict__ xdbb,
    const float* __restrict__ alf, const float* __restrict__ alb,
    const float* __restrict__ dwf, const float* __restrict__ dbf,
    const float* __restrict__ dwb, const float* __restrict__ dbb,
    float* __restrict__ hpart, float* __restrict__ sumd) {
    const int t = threadIdx.x;
    const int half = t & 1, dl = t >> 1;
    const int y = blockIdx.y;            // b*2+br
    const int b = y >> 1, br = y & 1;
    const int c = blockIdx.z;
    const int d = blockIdx.x * 128 + dl;
    const float* xc  = br ? xcb  : xcf;
    const float* xdb = br ? xdbb : xdbf;
    const float* Al  = br ? alb  : alf;
    const float* dw  = br ? dwb  : dwf;
    const float* dbi = br ? dbb  : dbf;

    float An[8];
    #pragma unroll
    for (int n = 0; n < 8; ++n)
        An[n] = -__expf(Al[(size_t)d * NST + half * 8 + n]);
    float wdt[DTR];
    #pragma unroll
    for (int k = 0; k < DTR; k += 4)
        *(float4*)&wdt[k] = *(const float4*)&dw[(size_t)d * DTR + k];
    float dbv = dbi[d];

    // batch-prefetch xc values for all CL steps (independent loads)
    float xr[CL];
    #pragma unroll
    for (int s = 0; s < CL; ++s) {
        int l = c * CL + s;
        xr[s] = (l < LF) ? xc[(size_t)(b * LF + l) * DIN + d] : 0.f;
    }

    __shared__ float sXD[CL][DTR];
    __shared__ float sB[CL][NST];
    for (int idx = t; idx < CL * DTR; idx += 256) {
        int s0 = idx / DTR, j0 = idx - s0 * DTR;
        int l0 = c * CL + s0;
        sXD[s0][j0] = (l0 < LF) ? xdb[(size_t)(b * LF + l0) * XDB + j0] : 0.f;
    }
    {
        int s0 = t >> 4, j0 = t & 15;
        int l0 = c * CL + s0;
        sB[s0][j0] = (l0 < LF) ? xdb[(size_t)(b * LF + l0) * XDB + DTR + j0] : 0.f;
    }
    __syncthreads();

    float h[8] = {};
    float sdt = 0.f;
    #pragma unroll
    for (int s = 0; s < CL; ++s) {
        int l = c * CL + s;
        if (l < LF) {
            float dtv = dbv;
            #pragma unroll
            for (int k = 0; k < DTR; ++k) dtv += sXD[s][k] * wdt[k];
            dtv = softplusf(dtv);
            sdt += dtv;
            float dtx = dtv * xr[s];
            #pragma unroll
            for (int n = 0; n < 8; ++n)
                h[n] = __expf(dtv * An[n]) * h[n] + dtx * sB[s][half * 8 + n];
        }
    }
    size_t base = (size_t)(c * 8 + y) * NST;
    #pragma unroll
    for (int n = 0; n < 8; ++n)
        hpart[(base + half * 8 + n) * DIN + d] = h[n];
    if (half == 0) sumd[(size_t)(c * 8 + y) * DIN + d] = sdt;
}

__global__ __launch_bounds__(256) void scanC_k(
    const float* __restrict__ xcf, const float* __restrict__ xcb,
    const float* __restrict__ xdbf, const float* __restrict__ xdbb,
    const float* __restrict__ xz,
    const float* __restrict__ alf, const float* __restrict__ dpf,
    const float* __restrict__ alb, const float* __restrict__ dpb,
    const float* __restrict__ dwf, const float* __restrict__ dbf,
    const float* __restrict__ dwb, const float* __restrict__ dbb,
    const float* __restrict__ hpart, const float* __restrict__ sumd,
    float* __restrict__ yf, float* __restrict__ yb) {
    const int t = threadIdx.x;
    const int half = t & 1, dl = t >> 1;
    const int y = blockIdx.y;
    const int b = y >> 1, br = y & 1;
    const int c = blockIdx.z;
    const int d = blockIdx.x * 128 + dl;
    const float* xc  = br ? xcb  : xcf;
    const float* xdb = br ? xdbb : xdbf;
    const float* Al  = br ? alb  : alf;
    const float* Dpp = br ? dpb  : dpf;
    const float* dw  = br ? dwb  : dwf;
    const float* dbi = br ? dbb  : dbf;
    float* yo        = br ? yb   : yf;

    float An[8];
    #pragma unroll
    for (int n = 0; n < 8; ++n)
        An[n] = -__expf(Al[(size_t)d * NST + half * 8 + n]);
    float wdt[DTR];
    #pragma unroll
    for (int k = 0; k < DTR; k += 4)
        *(float4*)&wdt[k] = *(const float4*)&dw[(size_t)d * DTR + k];
    float dbv = dbi[d];
    float Dv = Dpp[d];

    // batch-prefetch xc and z values for all CL steps (independent loads)
    float xr[CL], zr[CL];
    #pragma unroll
    for (int s = 0; s < CL; ++s) {
        int l = c * CL + s;
        if (l < LF) {
            xr[s] = xc[(size_t)(b * LF + l) * DIN + d];
            int zl = br ? (LF - 1 - l) : l;
            zr[s] = xz[(size_t)(b * LF + zl) * (2 * DIN) + DIN + d];
        } else { xr[s] = 0.f; zr[s] = 0.f; }
    }

    __shared__ float sXD[CL][DTR];
    __shared__ float sB[CL][NST];
    __shared__ float sC[CL][NST];
    for (int idx = t; idx < CL * DTR; idx += 256) {
        int s0 = idx / DTR, j0 = idx - s0 * DTR;
        int l0 = c * CL + s0;
        sXD[s0][j0] = (l0 < LF) ? xdb[(size_t)(b * LF + l0) * XDB + j0] : 0.f;
    }
    {
        int s0 = t >> 4, j0 = t & 15;
        int l0 = c * CL + s0;
        size_t rb = (size_t)(b * LF + l0) * XDB + DTR;
        sB[s0][j0] = (l0 < LF) ? xdb[rb + j0] : 0.f;
        sC[s0][j0] = (l0 < LF) ? xdb[rb + NST + j0] : 0.f;
    }
    __syncthreads();

    // prefix-combine earlier chunks (this thread's 8 states)
    float h[8] = {};
    for (int j = 0; j < c; ++j) {
        float sd = sumd[(size_t)(j * 8 + y) * DIN + d];
        size_t bj = (size_t)(j * 8 + y) * NST;
        #pragma unroll
        for (int n = 0; n < 8; ++n)
            h[n] = __expf(An[n] * sd) * h[n] + hpart[(bj + half * 8 + n) * DIN + d];
    }

    #pragma unroll
    for (int s = 0; s < CL; ++s) {
        int l = c * CL + s;
        if (l < LF) {
            int row = b * LF + l;
            float dtv = dbv;
            #pragma unroll
            for (int k = 0; k < DTR; ++k) dtv += sXD[s][k] * wdt[k];
            dtv = softplusf(dtv);
            float dtx = dtv * xr[s];
            float acc = 0.f;
            #pragma unroll
            for (int n = 0; n < 8; ++n) {
                h[n] = __expf(dtv * An[n]) * h[n] + dtx * sB[s][half * 8 + n];
                acc += h[n] * sC[s][half * 8 + n];
            }
            acc += __shfl_xor(acc, 1);   // combine the two halves' partial sums
            if (half == 0)
                yo[(size_t)row * DIN + d] = (acc + xr[s] * Dv) * siluf(zr[s]);
        }
    }
}

// final LN(row POS) + command MLP + add -> f32 out
__global__ __launch_bounds__(384) void final_k(
    const float* __restrict__ residual,
    const float* __restrict__ lnw, const float* __restrict__ lnb,
    const float* __restrict__ sv, const float* __restrict__ act,
    const float* __restrict__ cw1, const float* __restrict__ cb1,
    const float* __restrict__ cw2, const float* __restrict__ cb2,
    float* __restrict__ out) {
    int b = blockIdx.x, t = threadIdx.x;
    const float* x = residual + (size_t)(b * LF + POSROW) * DMODEL;
    float v = x[t];
    float s = v, sq = v * v;
    #pragma unroll
    for (int o = 32; o > 0; o >>= 1) {
        s += __shfl_down(s, o);
        sq += __shfl_down(sq, o);
    }
    __shared__ float ls[6], lq[6], hid[DMODEL], cmdin[20];
    if ((t & 63) == 0) { ls[t >> 6] = s; lq[t >> 6] = sq; }
    if (t < 20) cmdin[t] = (t < 16) ? sv[b * 16 + t] : act[b * 4 + t - 16];
    __syncthreads();
    float S = 0.f, Q = 0.f;
    #pragma unroll
    for (int w = 0; w < 6; ++w) { S += ls[w]; Q += lq[w]; }
    float mean = S * (1.f / 384.f);
    float var = Q * (1.f / 384.f) - mean * mean;
    float rs = rsqrtf(var + 1e-5f);
    float vis = (v - mean) * rs * lnw[t] + lnb[t];
    float a1 = cb1[t];
    #pragma unroll
    for (int k = 0; k < 20; ++k) a1 += cmdin[k] * cw1[t * 20 + k];
    hid[t] = fmaxf(a1, 0.f);
    __syncthreads();
    float a2 = cb2[t];
    for (int k = 0; k < DMODEL; ++k) a2 += hid[k] * cw2[t * DMODEL + k];
    out[b * DMODEL + t] = vis + a2;
}

extern "C" void kernel_launch(void* const* d_in, const int* in_sizes, int n_in,
                              void* d_out, int out_size, void* d_ws, size_t ws_size,
                              hipStream_t stream) {
    const float* depth_seq = (const float*)d_in[0];
    const float* state_vec = (const float*)d_in[1];
    const float* action    = (const float*)d_in[2];
    const float* patch_w   = (const float*)d_in[3];
    const float* patch_b   = (const float*)d_in[4];
    const float* cls_token = (const float*)d_in[5];
    const float* pos_embed = (const float*)d_in[6];
    const float* ln_w      = (const float*)d_in[7];
    const float* ln_b      = (const float*)d_in[8];
    const float* in_proj_w = (const float*)d_in[9];
    const float* conv_w    = (const float*)d_in[10];
    const float* conv_b    = (const float*)d_in[11];
    const float* conv_wb   = (const float*)d_in[12];
    const float* conv_bb   = (const float*)d_in[13];
    const float* xproj_w   = (const float*)d_in[14];
    const float* xproj_wb  = (const float*)d_in[15];
    const float* dtproj_w  = (const float*)d_in[16];
    const float* dtproj_b  = (const float*)d_in[17];
    const float* dtproj_wb = (const float*)d_in[18];
    const float* dtproj_bb = (const float*)d_in[19];
    const float* A_log     = (const float*)d_in[20];
    const float* A_logb    = (const float*)d_in[21];
    const float* Dp        = (const float*)d_in[22];
    const float* Dpb       = (const float*)d_in[23];
    const float* out_w     = (const float*)d_in[24];
    const float* lnf_w     = (const float*)d_in[25];
    const float* lnf_b     = (const float*)d_in[26];
    const float* cw1       = (const float*)d_in[27];
    const float* cb1       = (const float*)d_in[28];
    const float* cw2       = (const float*)d_in[29];
    const float* cb2       = (const float*)d_in[30];

    float* ws = (float*)d_ws;
    size_t o = 0;
    float* residual = ws + o; o += (size_t)MR * DMODEL;
    float* xz       = ws + o; o += (size_t)MR * 2 * DIN;
    float* xcf      = ws + o; o += (size_t)MR * DIN;
    float* xcb      = ws + o; o += (size_t)MR * DIN;
    float* xdbf     = ws + o; o += (size_t)MR * XDB;   // adjacent pair:
    float* xdbb     = ws + o; o += (size_t)MR * XDB;   // zeroed by in_proj
    float* yfb      = ws + o; o += (size_t)MR * DIN;
    float* ybb      = ws + o; o += (size_t)MR * DIN;
    float* hpart    = ws + o; o += (size_t)NC * 8 * NST * DIN;
    float* sumd     = ws + o; o += (size_t)NC * 8 * DIN;
    float2* stats   = (float2*)(ws + o); o += (size_t)MR * 2;
    (void)ws_size; (void)in_sizes; (void)n_in; (void)out_size;

    // patchify -> residual (bias + pos, cls gap), MFMA
    mgemm_k<1, 3><<<dim3(16, 6), 256, 0, stream>>>(
        nullptr, 0, patch_w, patch_b, residual, 1024, DMODEL, 256, 1,
        depth_seq, nullptr, pos_embed, nullptr, 0);
    cls_k<<<BB, DMODEL, 0, stream>>>(cls_token, pos_embed, residual);

    for (int i = 0; i < 4; ++i) {
        // LN stats: one pass per layer (proven R0 flow)
        lnstat_k<<<MR, 128, 0, stream>>>(residual, stats);
        // in_proj with fused LN (stats from buffer); also zeroes xdb for xp_k
        mgemm_k<3, 0><<<dim3(17, 24), 256, 0, stream>>>(
            residual, DMODEL, in_proj_w + (size_t)i * 2 * DIN * DMODEL, nullptr,
            xz, MR, 2 * DIN, DMODEL, 1,
            (const float*)stats, ln_w + (size_t)i * DMODEL, ln_b + (size_t)i * DMODEL,
            xdbf, 2 * MR * XDB);
        // fused conv+SiLU + xproj (writes xcf/xcb + atomic xdb partials)
        xp_k<<<dim3(17, NKC, 2), 256, 0, stream>>>(
            xz, conv_w + (size_t)i * DIN * 4, conv_b + (size_t)i * DIN,
            conv_wb + (size_t)i * DIN * 4, conv_bb + (size_t)i * DIN,
            xproj_w + (size_t)i * XDB * DIN, xproj_wb + (size_t)i * XDB * DIN,
            xcf, xcb, xdbf, xdbb);
        // chunked scan with fused dt-projection (split-NST: 816 blocks each)
        scanA_k<<<dim3(6, 8, NC), 256, 0, stream>>>(
            xcf, xcb, xdbf, xdbb,
            A_log + (size_t)i * DIN * NST, A_logb + (size_t)i * DIN * NST,
            dtproj_w + (size_t)i * DIN * DTR, dtproj_b + (size_t)i * DIN,
            dtproj_wb + (size_t)i * DIN * DTR, dtproj_bb + (size_t)i * DIN,
            hpart, sumd);
        scanC_k<<<dim3(6, 8, NC), 256, 0, stream>>>(
            xcf, xcb, xdbf, xdbb, xz,
            A_log + (size_t)i * DIN * NST, Dp + (size_t)i * DIN,
            A_logb + (size_t)i * DIN * NST, Dpb + (size_t)i * DIN,
            dtproj_w + (size_t)i * DIN * DTR, dtproj_b + (size_t)i * DIN,
            dtproj_wb + (size_t)i * DIN * DTR, dtproj_bb + (size_t)i * DIN,
            hpart, sumd, yfb, ybb);
        // out_proj flip-add, split-K 4, atomicAdd accumulate into residual
        mgemm_k<2, 4><<<dim3(17, 6 * 4), 256, 0, stream>>>(
            yfb, DIN, out_w + (size_t)i * DMODEL * DIN, nullptr,
            residual, MR, DMODEL, DIN, 4, nullptr, ybb, nullptr, nullptr, 0);
    }

    final_k<<<BB, DMODEL, 0, stream>>>(
        residual, lnf_w, lnf_b, state_vec, action, cw1, cb1, cw2, cb2,
        (float*)d_out);
}

// Round 8
// 553.302 us; speedup vs baseline: 1.4315x; 1.0372x over previous
//
#include <hip/hip_runtime.h>
#include <hip/hip_bf16.h>
#include <math.h>

#define BB 4
#define LF 257      // NTOK+1
#define MR 1028     // BB*LF
#define DMODEL 384
#define DIN 768
#define NST 16
#define DTR 24
#define XDB 56      // DTR + 2*N
#define POSROW 128
#define CL 16       // scan chunk length
#define NC 17       // ceil(LF/CL)
#define NKC 12      // xp_k split-K chunks (64 wide, single K64 stage each)

typedef __attribute__((ext_vector_type(8))) short short8;
typedef __attribute__((ext_vector_type(4))) float f32x4;

__device__ __forceinline__ float siluf(float v) { return v / (1.f + __expf(-v)); }
__device__ __forceinline__ float softplusf(float v) {
    return (v > 20.f) ? v : log1pf(__expf(v));
}
__device__ __forceinline__ short f2bf(float f) {
    unsigned u = __builtin_bit_cast(unsigned, f);
    unsigned r = (u + 0x7FFFu + ((u >> 16) & 1u)) >> 16;
    return (short)r;
}

// ---------------------------------------------------------------------------
// bf16-MFMA GEMM core over K range [kb,ke): C[m,n] (+)= sum A[m,k]*W[n,k].
// 64x64 tile, 4 waves (2x2). K-STEP 64: per step each thread stages 16 floats
// per matrix (4x float4, independent loads -> one latency), one barrier,
// 8 ds_read_b128 + 8 MFMA per wave. kgroup g in [0,8) holds k in [8g,8g+8);
// thread (m_s,q_s) stores groups 2q_s, 2q_s+1; MFMA reads kg = kh*4 + qq.
// AMODE: 1 patch gather, 2 flip-add, 3 LN-fused (gA=stats(mean,rstd))
// SMODE: 0 plain(+bias), 3 patchify store (bias+pos, cls gap), 4 atomicAdd
// ---------------------------------------------------------------------------
template<int AMODE, int SMODE>
__device__ __forceinline__ void mgemm_core(
    const float* __restrict__ A, int lda,
    const float* __restrict__ W,
    const float* __restrict__ bias,
    float* __restrict__ Cout, int M, int N, int K, int kb, int ke,
    int bm, int bn,
    const float* __restrict__ gA, const float* __restrict__ A2,
    const float* __restrict__ pos,
    short* __restrict__ Ab, short* __restrict__ Wb)
{
    const int tid = threadIdx.x;
    const int m_s = tid >> 2;
    const int q_s = tid & 3;
    const int lane = tid & 63;
    const int wv = tid >> 6;
    const int wm = (wv >> 1) * 32, wn = (wv & 1) * 32;
    const int qq = lane >> 4, lr = lane & 15;

    f32x4 acc[2][2];
    #pragma unroll
    for (int i = 0; i < 2; ++i)
        #pragma unroll
        for (int j = 0; j < 2; ++j)
            acc[i][j] = f32x4{0.f, 0.f, 0.f, 0.f};

    float2 stf = make_float2(0.f, 0.f);
    if (AMODE == 3) {
        int m = bm + m_s;
        if (m < M) stf = ((const float2*)gA)[m];
    }

    float4 pa[4], pw[4];
    const float4 z4 = make_float4(0.f, 0.f, 0.f, 0.f);

    auto loadA = [&](int k0) {
        int k = k0 + q_s * 16;
        int m = bm + m_s;
        if (AMODE == 1) {
            int b = m >> 8, t = m & 255;
            int gh = t >> 3, gw = t & 7;
            int p1 = k >> 4, p2 = k & 15;   // p2 == 0 for k0 % 64 == 0
            const float* src = &gA[(size_t)b * 65536 + gh * 2048 + p1 * 128 + gw * 16 + p2];
            pa[0] = ((const float4*)src)[0];
            pa[1] = ((const float4*)src)[1];
            pa[2] = ((const float4*)src)[2];
            pa[3] = ((const float4*)src)[3];
        } else if (AMODE == 2) {  // flip-add
            if (m < M && k < K) {
                int b = m / LF, l = m - b * LF;
                const float4* s1 = (const float4*)&A[(size_t)m * lda + k];
                const float4* s2 = (const float4*)&A2[(size_t)(b * LF + (LF - 1 - l)) * lda + k];
                #pragma unroll
                for (int i = 0; i < 4; ++i) {
                    float4 x = s1[i], y = s2[i];
                    pa[i] = make_float4(x.x + y.x, x.y + y.y, x.z + y.z, x.w + y.w);
                }
            } else { pa[0] = z4; pa[1] = z4; pa[2] = z4; pa[3] = z4; }
        } else {  // AMODE 3: LayerNorm fused during staging
            if (m < M && k < K) {
                const float4* rr = (const float4*)&A[(size_t)m * lda + k];
                const float4* ww = (const float4*)&A2[k];
                const float4* bb = (const float4*)&pos[k];
                #pragma unroll
                for (int i = 0; i < 4; ++i) {
                    float4 r = rr[i], w = ww[i], b0 = bb[i];
                    pa[i] = make_float4((r.x - stf.x) * stf.y * w.x + b0.x,
                                        (r.y - stf.x) * stf.y * w.y + b0.y,
                                        (r.z - stf.x) * stf.y * w.z + b0.z,
                                        (r.w - stf.x) * stf.y * w.w + b0.w);
                }
            } else { pa[0] = z4; pa[1] = z4; pa[2] = z4; pa[3] = z4; }
        }
    };
    auto loadW = [&](int k0) {
        int k = k0 + q_s * 16;
        int n = bn + m_s;
        if (n < N && k < K) {
            const float4* src = (const float4*)&W[(size_t)n * K + k];
            pw[0] = src[0]; pw[1] = src[1]; pw[2] = src[2]; pw[3] = src[3];
        } else { pw[0] = z4; pw[1] = z4; pw[2] = z4; pw[3] = z4; }
    };
    auto cvt8 = [&](float4 a, float4 b) -> short8 {
        short8 r;
        r[0] = f2bf(a.x); r[1] = f2bf(a.y); r[2] = f2bf(a.z); r[3] = f2bf(a.w);
        r[4] = f2bf(b.x); r[5] = f2bf(b.y); r[6] = f2bf(b.z); r[7] = f2bf(b.w);
        return r;
    };

    loadA(kb);
    loadW(kb);

    int s = 0;
    for (int k0 = kb; k0 < ke; k0 += 64, ++s) {
        const int buf = (s & 1) * 4096;
        *(short8*)&Ab[buf + ((2 * q_s) * 64 + m_s) * 8]     = cvt8(pa[0], pa[1]);
        *(short8*)&Ab[buf + ((2 * q_s + 1) * 64 + m_s) * 8] = cvt8(pa[2], pa[3]);
        *(short8*)&Wb[buf + ((2 * q_s) * 64 + m_s) * 8]     = cvt8(pw[0], pw[1]);
        *(short8*)&Wb[buf + ((2 * q_s + 1) * 64 + m_s) * 8] = cvt8(pw[2], pw[3]);
        __syncthreads();
        if (k0 + 64 < ke) { loadA(k0 + 64); loadW(k0 + 64); }
        #pragma unroll
        for (int kh = 0; kh < 2; ++kh) {
            const int kg = kh * 4 + qq;
            short8 af0 = *(const short8*)&Ab[buf + (kg * 64 + wm + lr) * 8];
            short8 af1 = *(const short8*)&Ab[buf + (kg * 64 + wm + 16 + lr) * 8];
            short8 wf0 = *(const short8*)&Wb[buf + (kg * 64 + wn + lr) * 8];
            short8 wf1 = *(const short8*)&Wb[buf + (kg * 64 + wn + 16 + lr) * 8];
            acc[0][0] = __builtin_amdgcn_mfma_f32_16x16x32_bf16(af0, wf0, acc[0][0], 0, 0, 0);
            acc[0][1] = __builtin_amdgcn_mfma_f32_16x16x32_bf16(af0, wf1, acc[0][1], 0, 0, 0);
            acc[1][0] = __builtin_amdgcn_mfma_f32_16x16x32_bf16(af1, wf0, acc[1][0], 0, 0, 0);
            acc[1][1] = __builtin_amdgcn_mfma_f32_16x16x32_bf16(af1, wf1, acc[1][1], 0, 0, 0);
        }
    }

    #pragma unroll
    for (int mi = 0; mi < 2; ++mi) {
        #pragma unroll
        for (int ni = 0; ni < 2; ++ni) {
            int col = bn + wn + ni * 16 + lr;
            if (col >= N) continue;
            #pragma unroll
            for (int r = 0; r < 4; ++r) {
                int row = bm + wm + mi * 16 + qq * 4 + r;
                if (row >= M) continue;
                float v = acc[mi][ni][r];
                if (SMODE == 0) {
                    if (bias) v += bias[col];
                    Cout[(size_t)row * N + col] = v;
                } else if (SMODE == 3) {
                    int b = row >> 8, t = row & 255;
                    int l = (t < POSROW) ? t : t + 1;
                    v += bias[col] + pos[(size_t)l * DMODEL + col];
                    Cout[(size_t)(b * LF + l) * DMODEL + col] = v;
                } else {  // SMODE 4
                    atomicAdd(&Cout[(size_t)row * N + col], v);
                }
            }
        }
    }
}

template<int AMODE, int SMODE>
__global__ __launch_bounds__(256) void mgemm_k(
    const float* __restrict__ A, int lda,
    const float* __restrict__ W, const float* __restrict__ bias,
    float* __restrict__ Cout, int M, int N, int K, int KS,
    const float* __restrict__ gA, const float* __restrict__ A2,
    const float* __restrict__ pos,
    float* __restrict__ zbuf, int zcount)
{
    __shared__ __align__(16) short Ab[2 * 4096];
    __shared__ __align__(16) short Wb[2 * 4096];
    if (zbuf) {
        int nthr = gridDim.x * gridDim.y * 256;
        int gi = (blockIdx.x + blockIdx.y * gridDim.x) * 256 + threadIdx.x;
        for (int i = gi; i < zcount; i += nthr) zbuf[i] = 0.f;
    }
    // XCD-aware bijective swizzle (nwg % 8 == 0 for all our grids)
    int nwg = gridDim.x * gridDim.y;
    int lin = blockIdx.x + blockIdx.y * gridDim.x;
    if ((nwg & 7) == 0) {
        int ch = nwg >> 3;
        lin = (lin & 7) * ch + (lin >> 3);
    }
    int bx = lin % gridDim.x;
    int by = lin / gridDim.x;
    int ntile = by / KS, ks = by % KS;
    int chunk = K / KS;
    mgemm_core<AMODE, SMODE>(A, lda, W, bias, Cout, M, N, K,
                             ks * chunk, ks * chunk + chunk, bx * 64, ntile * 64,
                             gA, A2, pos, Ab, Wb);
}

// ---------------------------------------------------------------------------
// Fused conv(K=4)+SiLU -> xproj MFMA. grid (17 m-tiles, NKC=12 k-chunks, 2 br).
// SINGLE K64 stage per block: one staging burst (all loads independent ->
// one exposed latency), one barrier, 8 MFMAs. No loop, no double buffer.
// Same LDS layout as mgemm K64 (kgroups 2q_s, 2q_s+1 per thread).
// ---------------------------------------------------------------------------
__global__ __launch_bounds__(256) void xp_k(
    const float* __restrict__ xz,
    const float* __restrict__ cwf, const float* __restrict__ cbf,
    const float* __restrict__ cwb, const float* __restrict__ cbb,
    const float* __restrict__ Wf, const float* __restrict__ Wb,
    float* __restrict__ xcf, float* __restrict__ xcb,
    float* __restrict__ xdbf, float* __restrict__ xdbb)
{
    __shared__ __align__(16) short Ash[4096];
    __shared__ __align__(16) short Wsh[4096];
    const int br = blockIdx.z;
    const int kcid = blockIdx.y;           // 0..NKC-1, 64-wide d-chunk
    const float* cw = br ? cwb : cwf;
    const float* cbv = br ? cbb : cbf;
    const float* W  = br ? Wb  : Wf;
    float* xco      = br ? xcb : xcf;
    float* xdo      = br ? xdbb : xdbf;

    const int tid = threadIdx.x;
    const int m_s = tid >> 2, q_s = tid & 3;
    const int bm = blockIdx.x * 64;
    const int kb = kcid * 64;
    const int lane = tid & 63, wv = tid >> 6;
    const int wm = (wv >> 1) * 32, wn = (wv & 1) * 32;
    const int qq = lane >> 4, lr = lane & 15;
    const int m = bm + m_s;
    const bool mok = (m < MR);
    int b = 0, l = 0;
    if (mok) { b = m / LF; l = m - b * LF; }

    // ---- conv+SiLU for 16 d-values [d0, d0+16) ----
    const int d0 = kb + q_s * 16;
    float a16[16];
    if (mok) {
        #pragma unroll
        for (int i = 0; i < 4; ++i) {
            float4 c = ((const float4*)&cbv[d0])[i];
            a16[4 * i] = c.x; a16[4 * i + 1] = c.y;
            a16[4 * i + 2] = c.z; a16[4 * i + 3] = c.w;
        }
        float wreg[16][4];
        #pragma unroll
        for (int j = 0; j < 16; ++j)
            *(float4*)wreg[j] = *(const float4*)&cw[(d0 + j) * 4];
        #pragma unroll
        for (int kk = 0; kk < 4; ++kk) {
            int li = l - 3 + kk;
            if (li >= 0) {
                int srow = br ? (b * LF + (LF - 1 - li)) : (b * LF + li);
                const float4* xp = (const float4*)&xz[(size_t)srow * 2 * DIN + d0];
                #pragma unroll
                for (int i = 0; i < 4; ++i) {
                    float4 x = xp[i];
                    a16[4 * i]     += x.x * wreg[4 * i][kk];
                    a16[4 * i + 1] += x.y * wreg[4 * i + 1][kk];
                    a16[4 * i + 2] += x.z * wreg[4 * i + 2][kk];
                    a16[4 * i + 3] += x.w * wreg[4 * i + 3][kk];
                }
            }
        }
        #pragma unroll
        for (int j = 0; j < 16; ++j) a16[j] = siluf(a16[j]);
    } else {
        #pragma unroll
        for (int j = 0; j < 16; ++j) a16[j] = 0.f;
    }

    // ---- W fragment (16 k-values for row m_s) ----
    float4 pw[4];
    {
        const float4 z4 = make_float4(0.f, 0.f, 0.f, 0.f);
        if (m_s < XDB) {
            const float4* src = (const float4*)&W[(size_t)m_s * DIN + kb + q_s * 16];
            pw[0] = src[0]; pw[1] = src[1]; pw[2] = src[2]; pw[3] = src[3];
        } else { pw[0] = z4; pw[1] = z4; pw[2] = z4; pw[3] = z4; }
    }

    auto cvt8a = [&](int o) -> short8 {
        short8 r;
        #pragma unroll
        for (int j = 0; j < 8; ++j) r[j] = f2bf(a16[o + j]);
        return r;
    };
    auto cvt8w = [&](float4 a, float4 b) -> short8 {
        short8 r;
        r[0] = f2bf(a.x); r[1] = f2bf(a.y); r[2] = f2bf(a.z); r[3] = f2bf(a.w);
        r[4] = f2bf(b.x); r[5] = f2bf(b.y); r[6] = f2bf(b.z); r[7] = f2bf(b.w);
        return r;
    };

    *(short8*)&Ash[((2 * q_s) * 64 + m_s) * 8]     = cvt8a(0);
    *(short8*)&Ash[((2 * q_s + 1) * 64 + m_s) * 8] = cvt8a(8);
    *(short8*)&Wsh[((2 * q_s) * 64 + m_s) * 8]     = cvt8w(pw[0], pw[1]);
    *(short8*)&Wsh[((2 * q_s + 1) * 64 + m_s) * 8] = cvt8w(pw[2], pw[3]);
    if (mok) {  // side-product: materialize xc for the scan kernels
        float4* dst = (float4*)&xco[(size_t)m * DIN + d0];
        dst[0] = make_float4(a16[0], a16[1], a16[2], a16[3]);
        dst[1] = make_float4(a16[4], a16[5], a16[6], a16[7]);
        dst[2] = make_float4(a16[8], a16[9], a16[10], a16[11]);
        dst[3] = make_float4(a16[12], a16[13], a16[14], a16[15]);
    }
    __syncthreads();

    f32x4 acc[2][2];
    #pragma unroll
    for (int i = 0; i < 2; ++i)
        #pragma unroll
        for (int j = 0; j < 2; ++j)
            acc[i][j] = f32x4{0.f, 0.f, 0.f, 0.f};

    #pragma unroll
    for (int kh = 0; kh < 2; ++kh) {
        const int kg = kh * 4 + qq;
        short8 af0 = *(const short8*)&Ash[(kg * 64 + wm + lr) * 8];
        short8 af1 = *(const short8*)&Ash[(kg * 64 + wm + 16 + lr) * 8];
        short8 wf0 = *(const short8*)&Wsh[(kg * 64 + wn + lr) * 8];
        short8 wf1 = *(const short8*)&Wsh[(kg * 64 + wn + 16 + lr) * 8];
        acc[0][0] = __builtin_amdgcn_mfma_f32_16x16x32_bf16(af0, wf0, acc[0][0], 0, 0, 0);
        acc[0][1] = __builtin_amdgcn_mfma_f32_16x16x32_bf16(af0, wf1, acc[0][1], 0, 0, 0);
        acc[1][0] = __builtin_amdgcn_mfma_f32_16x16x32_bf16(af1, wf0, acc[1][0], 0, 0, 0);
        acc[1][1] = __builtin_amdgcn_mfma_f32_16x16x32_bf16(af1, wf1, acc[1][1], 0, 0, 0);
    }

    #pragma unroll
    for (int mi = 0; mi < 2; ++mi) {
        #pragma unroll
        for (int ni = 0; ni < 2; ++ni) {
            int col = wn + ni * 16 + lr;
            if (col >= XDB) continue;
            #pragma unroll
            for (int r = 0; r < 4; ++r) {
                int row = bm + wm + mi * 16 + qq * 4 + r;
                if (row >= MR) continue;
                atomicAdd(&xdo[(size_t)row * XDB + col], acc[mi][ni][r]);
            }
        }
    }
}

// cls row: residual[b, 128, :] = cls + pos[128]
__global__ void cls_k(const float* __restrict__ cls, const float* __restrict__ pos,
                      float* __restrict__ residual) {
    int b = blockIdx.x, t = threadIdx.x;
    residual[(size_t)(b * LF + POSROW) * DMODEL + t] =
        cls[t] + pos[(size_t)POSROW * DMODEL + t];
}

// row-wise layernorm STATS over 384 -> (mean, rstd) per row
__global__ __launch_bounds__(128) void lnstat_k(const float* __restrict__ X,
                                                float2* __restrict__ st) {
    int r = blockIdx.x;
    const float* x = X + (size_t)r * DMODEL;
    int t = threadIdx.x;
    float v0 = x[t], v1 = x[t + 128], v2 = x[t + 256];
    float s = v0 + v1 + v2;
    float sq = v0 * v0 + v1 * v1 + v2 * v2;
    #pragma unroll
    for (int o = 32; o > 0; o >>= 1) {
        s += __shfl_down(s, o);
        sq += __shfl_down(sq, o);
    }
    __shared__ float ls[2], lq[2];
    if ((t & 63) == 0) { ls[t >> 6] = s; lq[t >> 6] = sq; }
    __syncthreads();
    if (t == 0) {
        float S = ls[0] + ls[1], Q = lq[0] + lq[1];
        float mean = S * (1.f / 384.f);
        float var = Q * (1.f / 384.f) - mean * mean;
        st[r] = make_float2(mean, rsqrtf(var + 1e-5f));
    }
}

// ---------------------------------------------------------------------------
// Chunked scan, SPLIT-NST: 2 paired lanes per d-column, 8 states each.
// xcv/zv batch-prefetched into registers BEFORE the serial loop.
// ---------------------------------------------------------------------------
__global__ __launch_bounds__(256) void scanA_k(
    const float* __restrict__ xcf, const float* __restrict__ xcb,
    const float* __restrict__ xdbf, const float* __restrict__ xdbb,
    const float* __restrict__ alf, const float* __restrict__ alb,
    const float* __restrict__ dwf, const float* __restrict__ dbf,
    const float* __restrict__ dwb, const float* __restrict__ dbb,
    float* __restrict__ hpart, float* __restrict__ sumd) {
    const int t = threadIdx.x;
    const int half = t & 1, dl = t >> 1;
    const int y = blockIdx.y;            // b*2+br
    const int b = y >> 1, br = y & 1;
    const int c = blockIdx.z;
    const int d = blockIdx.x * 128 + dl;
    const float* xc  = br ? xcb  : xcf;
    const float* xdb = br ? xdbb : xdbf;
    const float* Al  = br ? alb  : alf;
    const float* dw  = br ? dwb  : dwf;
    const float* dbi = br ? dbb  : dbf;

    float An[8];
    #pragma unroll
    for (int n = 0; n < 8; ++n)
        An[n] = -__expf(Al[(size_t)d * NST + half * 8 + n]);
    float wdt[DTR];
    #pragma unroll
    for (int k = 0; k < DTR; k += 4)
        *(float4*)&wdt[k] = *(const float4*)&dw[(size_t)d * DTR + k];
    float dbv = dbi[d];

    // batch-prefetch xc values for all CL steps (independent loads)
    float xr[CL];
    #pragma unroll
    for (int s = 0; s < CL; ++s) {
        int l = c * CL + s;
        xr[s] = (l < LF) ? xc[(size_t)(b * LF + l) * DIN + d] : 0.f;
    }

    __shared__ float sXD[CL][DTR];
    __shared__ float sB[CL][NST];
    for (int idx = t; idx < CL * DTR; idx += 256) {
        int s0 = idx / DTR, j0 = idx - s0 * DTR;
        int l0 = c * CL + s0;
        sXD[s0][j0] = (l0 < LF) ? xdb[(size_t)(b * LF + l0) * XDB + j0] : 0.f;
    }
    {
        int s0 = t >> 4, j0 = t & 15;
        int l0 = c * CL + s0;
        sB[s0][j0] = (l0 < LF) ? xdb[(size_t)(b * LF + l0) * XDB + DTR + j0] : 0.f;
    }
    __syncthreads();

    float h[8] = {};
    float sdt = 0.f;
    #pragma unroll
    for (int s = 0; s < CL; ++s) {
        int l = c * CL + s;
        if (l < LF) {
            float dtv = dbv;
            #pragma unroll
            for (int k = 0; k < DTR; ++k) dtv += sXD[s][k] * wdt[k];
            dtv = softplusf(dtv);
            sdt += dtv;
            float dtx = dtv * xr[s];
            #pragma unroll
            for (int n = 0; n < 8; ++n)
                h[n] = __expf(dtv * An[n]) * h[n] + dtx * sB[s][half * 8 + n];
        }
    }
    size_t base = (size_t)(c * 8 + y) * NST;
    #pragma unroll
    for (int n = 0; n < 8; ++n)
        hpart[(base + half * 8 + n) * DIN + d] = h[n];
    if (half == 0) sumd[(size_t)(c * 8 + y) * DIN + d] = sdt;
}

__global__ __launch_bounds__(256) void scanC_k(
    const float* __restrict__ xcf, const float* __restrict__ xcb,
    const float* __restrict__ xdbf, const float* __restrict__ xdbb,
    const float* __restrict__ xz,
    const float* __restrict__ alf, const float* __restrict__ dpf,
    const float* __restrict__ alb, const float* __restrict__ dpb,
    const float* __restrict__ dwf, const float* __restrict__ dbf,
    const float* __restrict__ dwb, const float* __restrict__ dbb,
    const float* __restrict__ hpart, const float* __restrict__ sumd,
    float* __restrict__ yf, float* __restrict__ yb) {
    const int t = threadIdx.x;
    const int half = t & 1, dl = t >> 1;
    const int y = blockIdx.y;
    const int b = y >> 1, br = y & 1;
    const int c = blockIdx.z;
    const int d = blockIdx.x * 128 + dl;
    const float* xc  = br ? xcb  : xcf;
    const float* xdb = br ? xdbb : xdbf;
    const float* Al  = br ? alb  : alf;
    const float* Dpp = br ? dpb  : dpf;
    const float* dw  = br ? dwb  : dwf;
    const float* dbi = br ? dbb  : dbf;
    float* yo        = br ? yb   : yf;

    float An[8];
    #pragma unroll
    for (int n = 0; n < 8; ++n)
        An[n] = -__expf(Al[(size_t)d * NST + half * 8 + n]);
    float wdt[DTR];
    #pragma unroll
    for (int k = 0; k < DTR; k += 4)
        *(float4*)&wdt[k] = *(const float4*)&dw[(size_t)d * DTR + k];
    float dbv = dbi[d];
    float Dv = Dpp[d];

    // batch-prefetch xc and z values for all CL steps (independent loads)
    float xr[CL], zr[CL];
    #pragma unroll
    for (int s = 0; s < CL; ++s) {
        int l = c * CL + s;
        if (l < LF) {
            xr[s] = xc[(size_t)(b * LF + l) * DIN + d];
            int zl = br ? (LF - 1 - l) : l;
            zr[s] = xz[(size_t)(b * LF + zl) * (2 * DIN) + DIN + d];
        } else { xr[s] = 0.f; zr[s] = 0.f; }
    }

    __shared__ float sXD[CL][DTR];
    __shared__ float sB[CL][NST];
    __shared__ float sC[CL][NST];
    for (int idx = t; idx < CL * DTR; idx += 256) {
        int s0 = idx / DTR, j0 = idx - s0 * DTR;
        int l0 = c * CL + s0;
        sXD[s0][j0] = (l0 < LF) ? xdb[(size_t)(b * LF + l0) * XDB + j0] : 0.f;
    }
    {
        int s0 = t >> 4, j0 = t & 15;
        int l0 = c * CL + s0;
        size_t rb = (size_t)(b * LF + l0) * XDB + DTR;
        sB[s0][j0] = (l0 < LF) ? xdb[rb + j0] : 0.f;
        sC[s0][j0] = (l0 < LF) ? xdb[rb + NST + j0] : 0.f;
    }
    __syncthreads();

    // prefix-combine earlier chunks (this thread's 8 states)
    float h[8] = {};
    for (int j = 0; j < c; ++j) {
        float sd = sumd[(size_t)(j * 8 + y) * DIN + d];
        size_t bj = (size_t)(j * 8 + y) * NST;
        #pragma unroll
        for (int n = 0; n < 8; ++n)
            h[n] = __expf(An[n] * sd) * h[n] + hpart[(bj + half * 8 + n) * DIN + d];
    }

    #pragma unroll
    for (int s = 0; s < CL; ++s) {
        int l = c * CL + s;
        if (l < LF) {
            int row = b * LF + l;
            float dtv = dbv;
            #pragma unroll
            for (int k = 0; k < DTR; ++k) dtv += sXD[s][k] * wdt[k];
            dtv = softplusf(dtv);
            float dtx = dtv * xr[s];
            float acc = 0.f;
            #pragma unroll
            for (int n = 0; n < 8; ++n) {
                h[n] = __expf(dtv * An[n]) * h[n] + dtx * sB[s][half * 8 + n];
                acc += h[n] * sC[s][half * 8 + n];
            }
            acc += __shfl_xor(acc, 1);   // combine the two halves' partial sums
            if (half == 0)
                yo[(size_t)row * DIN + d] = (acc + xr[s] * Dv) * siluf(zr[s]);
        }
    }
}

// final LN(row POS) + command MLP + add -> f32 out
__global__ __launch_bounds__(384) void final_k(
    const float* __restrict__ residual,
    const float* __restrict__ lnw, const float* __restrict__ lnb,
    const float* __restrict__ sv, const float* __restrict__ act,
    const float* __restrict__ cw1, const float* __restrict__ cb1,
    const float* __restrict__ cw2, const float* __restrict__ cb2,
    float* __restrict__ out) {
    int b = blockIdx.x, t = threadIdx.x;
    const float* x = residual + (size_t)(b * LF + POSROW) * DMODEL;
    float v = x[t];
    float s = v, sq = v * v;
    #pragma unroll
    for (int o = 32; o > 0; o >>= 1) {
        s += __shfl_down(s, o);
        sq += __shfl_down(sq, o);
    }
    __shared__ float ls[6], lq[6], hid[DMODEL], cmdin[20];
    if ((t & 63) == 0) { ls[t >> 6] = s; lq[t >> 6] = sq; }
    if (t < 20) cmdin[t] = (t < 16) ? sv[b * 16 + t] : act[b * 4 + t - 16];
    __syncthreads();
    float S = 0.f, Q = 0.f;
    #pragma unroll
    for (int w = 0; w < 6; ++w) { S += ls[w]; Q += lq[w]; }
    float mean = S * (1.f / 384.f);
    float var = Q * (1.f / 384.f) - mean * mean;
    float rs = rsqrtf(var + 1e-5f);
    float vis = (v - mean) * rs * lnw[t] + lnb[t];
    float a1 = cb1[t];
    #pragma unroll
    for (int k = 0; k < 20; ++k) a1 += cmdin[k] * cw1[t * 20 + k];
    hid[t] = fmaxf(a1, 0.f);
    __syncthreads();
    float a2 = cb2[t];
    for (int k = 0; k < DMODEL; ++k) a2 += hid[k] * cw2[t * DMODEL + k];
    out[b * DMODEL + t] = vis + a2;
}

extern "C" void kernel_launch(void* const* d_in, const int* in_sizes, int n_in,
                              void* d_out, int out_size, void* d_ws, size_t ws_size,
                              hipStream_t stream) {
    const float* depth_seq = (const float*)d_in[0];
    const float* state_vec = (const float*)d_in[1];
    const float* action    = (const float*)d_in[2];
    const float* patch_w   = (const float*)d_in[3];
    const float* patch_b   = (const float*)d_in[4];
    const float* cls_token = (const float*)d_in[5];
    const float* pos_embed = (const float*)d_in[6];
    const float* ln_w      = (const float*)d_in[7];
    const float* ln_b      = (const float*)d_in[8];
    const float* in_proj_w = (const float*)d_in[9];
    const float* conv_w    = (const float*)d_in[10];
    const float* conv_b    = (const float*)d_in[11];
    const float* conv_wb   = (const float*)d_in[12];
    const float* conv_bb   = (const float*)d_in[13];
    const float* xproj_w   = (const float*)d_in[14];
    const float* xproj_wb  = (const float*)d_in[15];
    const float* dtproj_w  = (const float*)d_in[16];
    const float* dtproj_b  = (const float*)d_in[17];
    const float* dtproj_wb = (const float*)d_in[18];
    const float* dtproj_bb = (const float*)d_in[19];
    const float* A_log     = (const float*)d_in[20];
    const float* A_logb    = (const float*)d_in[21];
    const float* Dp        = (const float*)d_in[22];
    const float* Dpb       = (const float*)d_in[23];
    const float* out_w     = (const float*)d_in[24];
    const float* lnf_w     = (const float*)d_in[25];
    const float* lnf_b     = (const float*)d_in[26];
    const float* cw1       = (const float*)d_in[27];
    const float* cb1       = (const float*)d_in[28];
    const float* cw2       = (const float*)d_in[29];
    const float* cb2       = (const float*)d_in[30];

    float* ws = (float*)d_ws;
    size_t o = 0;
    float* residual = ws + o; o += (size_t)MR * DMODEL;
    float* xz       = ws + o; o += (size_t)MR * 2 * DIN;
    float* xcf      = ws + o; o += (size_t)MR * DIN;
    float* xcb      = ws + o; o += (size_t)MR * DIN;
    float* xdbf     = ws + o; o += (size_t)MR * XDB;   // adjacent pair:
    float* xdbb     = ws + o; o += (size_t)MR * XDB;   // zeroed by in_proj
    float* yfb      = ws + o; o += (size_t)MR * DIN;
    float* ybb      = ws + o; o += (size_t)MR * DIN;
    float* hpart    = ws + o; o += (size_t)NC * 8 * NST * DIN;
    float* sumd     = ws + o; o += (size_t)NC * 8 * DIN;
    float2* stats   = (float2*)(ws + o); o += (size_t)MR * 2;
    (void)ws_size; (void)in_sizes; (void)n_in; (void)out_size;

    // patchify -> residual (bias + pos, cls gap), MFMA
    mgemm_k<1, 3><<<dim3(16, 6), 256, 0, stream>>>(
        nullptr, 0, patch_w, patch_b, residual, 1024, DMODEL, 256, 1,
        depth_seq, nullptr, pos_embed, nullptr, 0);
    cls_k<<<BB, DMODEL, 0, stream>>>(cls_token, pos_embed, residual);

    for (int i = 0; i < 4; ++i) {
        // LN stats: one pass per layer (proven R0 flow)
        lnstat_k<<<MR, 128, 0, stream>>>(residual, stats);
        // in_proj with fused LN (stats from buffer); also zeroes xdb for xp_k
        mgemm_k<3, 0><<<dim3(17, 24), 256, 0, stream>>>(
            residual, DMODEL, in_proj_w + (size_t)i * 2 * DIN * DMODEL, nullptr,
            xz, MR, 2 * DIN, DMODEL, 1,
            (const float*)stats, ln_w + (size_t)i * DMODEL, ln_b + (size_t)i * DMODEL,
            xdbf, 2 * MR * XDB);
        // fused conv+SiLU + xproj (single K64 stage per block, NKC=12)
        xp_k<<<dim3(17, NKC, 2), 256, 0, stream>>>(
            xz, conv_w + (size_t)i * DIN * 4, conv_b + (size_t)i * DIN,
            conv_wb + (size_t)i * DIN * 4, conv_bb + (size_t)i * DIN,
            xproj_w + (size_t)i * XDB * DIN, xproj_wb + (size_t)i * XDB * DIN,
            xcf, xcb, xdbf, xdbb);
        // chunked scan with fused dt-projection (split-NST: 816 blocks each)
        scanA_k<<<dim3(6, 8, NC), 256, 0, stream>>>(
            xcf, xcb, xdbf, xdbb,
            A_log + (size_t)i * DIN * NST, A_logb + (size_t)i * DIN * NST,
            dtproj_w + (size_t)i * DIN * DTR, dtproj_b + (size_t)i * DIN,
            dtproj_wb + (size_t)i * DIN * DTR, dtproj_bb + (size_t)i * DIN,
            hpart, sumd);
        scanC_k<<<dim3(6, 8, NC), 256, 0, stream>>>(
            xcf, xcb, xdbf, xdbb, xz,
            A_log + (size_t)i * DIN * NST, Dp + (size_t)i * DIN,
            A_logb + (size_t)i * DIN * NST, Dpb + (size_t)i * DIN,
            dtproj_w + (size_t)i * DIN * DTR, dtproj_b + (size_t)i * DIN,
            dtproj_wb + (size_t)i * DIN * DTR, dtproj_bb + (size_t)i * DIN,
            hpart, sumd, yfb, ybb);
        // out_proj flip-add, split-K 4, atomicAdd accumulate into residual
        mgemm_k<2, 4><<<dim3(17, 6 * 4), 256, 0, stream>>>(
            yfb, DIN, out_w + (size_t)i * DMODEL * DIN, nullptr,
            residual, MR, DMODEL, DIN, 4, nullptr, ybb, nullptr, nullptr, 0);
    }

    final_k<<<BB, DMODEL, 0, stream>>>(
        residual, lnf_w, lnf_b, state_vec, action, cw1, cb1, cw2, cb2,
        (float*)d_out);
}